// Round 7
// baseline (413.953 us; speedup 1.0000x reference)
//
#include <hip/hip_runtime.h>

#define B_   2
#define S_   2048
#define HID_ 2048
#define NH_  16
#define HD_  128
#define MAXTOK_ 2048

typedef float  f32x4  __attribute__((ext_vector_type(4)));
typedef __bf16 bf16x8 __attribute__((ext_vector_type(8)));
typedef unsigned short u16x8 __attribute__((ext_vector_type(8)));

__device__ __forceinline__ unsigned short f2bf(float f) {
  union { float fv; unsigned u; } v; v.fv = f;
  unsigned r = v.u + 0x7FFFu + ((v.u >> 16) & 1u);  // RNE
  return (unsigned short)(r >> 16);
}
__device__ __forceinline__ float bf2f(unsigned short h) {
  union { unsigned u; float fv; } v; v.u = ((unsigned)h) << 16;
  return v.fv;
}

// async global->LDS, 16B per lane (LDS dst must be linear/contiguous)
__device__ __forceinline__ void gload16(const void* g, void* lds) {
  __builtin_amdgcn_global_load_lds(
      (const __attribute__((address_space(1))) void*)g,
      (__attribute__((address_space(3))) void*)lds, 16, 0, 0);
}

// ---------------- fused cast fp32 -> bf16 for hidden + 4 weights ----------------
#define H4_ (B_ * S_ * HID_ / 4)
#define W4_ (HID_ * HID_ / 4)
__global__ void cast_all(const float* __restrict__ h,  const float* __restrict__ wq,
                         const float* __restrict__ wk, const float* __restrict__ wv,
                         const float* __restrict__ wo,
                         unsigned short* __restrict__ xb,  unsigned short* __restrict__ wqb,
                         unsigned short* __restrict__ wkb, unsigned short* __restrict__ wvb,
                         unsigned short* __restrict__ wob) {
  const int total = H4_ + 4 * W4_;
  int i = blockIdx.x * blockDim.x + threadIdx.x;
  int stride = gridDim.x * blockDim.x;
  for (; i < total; i += stride) {
    const float* src; unsigned short* dst; int j;
    if (i < H4_) { src = h; dst = xb; j = i; }
    else {
      int k = i - H4_, wsel = k >> 20;  // W4_ = 2^20
      j = k & (W4_ - 1);
      src = (wsel == 0) ? wq : (wsel == 1) ? wk : (wsel == 2) ? wv : wo;
      dst = (wsel == 0) ? wqb : (wsel == 1) ? wkb : (wsel == 2) ? wvb : wob;
    }
    float4 v = ((const float4*)src)[j];
    ushort4 o;
    o.x = f2bf(v.x); o.y = f2bf(v.y); o.z = f2bf(v.z); o.w = f2bf(v.w);
    ((ushort4*)dst)[j] = o;
  }
}

// ---------------- fused QKV projection: 256x192 tile, BK=64, 4-phase/K-tile ----------------
// Round-3 verified structure (107 us, MfmaUtil 40%, conflicts 0).
#define QKV_STG(gp, lp, rb) gload16((gp) + (size_t)(rb) * 2048, (lp) + (rb) * 64)

#define QKV_LOADA(Q) do { \
  _Pragma("unroll") \
  for (int mi_ = 0; mi_ < 2; ++mi_) { \
    const char* rp_ = (const char*)Acur + (size_t)((wm + (Q) * 32 + mi_ * 16 + rowq) * 128); \
    af[mi_][0] = *(const bf16x8*)(rp_ + cb0); \
    af[mi_][1] = *(const bf16x8*)(rp_ + cb1); \
  } } while (0)

#define QKV_LOADB() do { \
  _Pragma("unroll") \
  for (int ni_ = 0; ni_ < 3; ++ni_) { \
    const char* rp_ = (const char*)Bcur + (size_t)((wn + ni_ * 16 + rowq) * 128); \
    bfr[ni_][0] = *(const bf16x8*)(rp_ + cb0); \
    bfr[ni_][1] = *(const bf16x8*)(rp_ + cb1); \
  } } while (0)

#define QKV_MFMA(Q) do { \
  _Pragma("unroll") \
  for (int mi_ = 0; mi_ < 2; ++mi_) { \
    _Pragma("unroll") \
    for (int ni_ = 0; ni_ < 3; ++ni_) { \
      f32x4 c_ = acc[(Q) * 2 + mi_][ni_]; \
      c_ = __builtin_amdgcn_mfma_f32_16x16x32_bf16(af[mi_][0], bfr[ni_][0], c_, 0, 0, 0); \
      c_ = __builtin_amdgcn_mfma_f32_16x16x32_bf16(af[mi_][1], bfr[ni_][1], c_, 0, 0, 0); \
      acc[(Q) * 2 + mi_][ni_] = c_; \
    } } } while (0)

#define QKV_BAR    asm volatile("s_barrier" ::: "memory")
#define QKV_VMC4   asm volatile("s_waitcnt vmcnt(4)" ::: "memory")
#define QKV_VMC2   asm volatile("s_waitcnt vmcnt(2)" ::: "memory")
#define QKV_VMC0   asm volatile("s_waitcnt vmcnt(0)" ::: "memory")

__global__ __launch_bounds__(512, 2)
void gemm_qkv(const unsigned short* __restrict__ A,
              const unsigned short* __restrict__ Bw,
              unsigned short* __restrict__ Qb,
              unsigned short* __restrict__ Kb,
              unsigned short* __restrict__ Vtmp) {
  const int K = HID_;       // 2048
  const int NT = K / 64;    // 32 K-tiles
  __shared__ __align__(16) unsigned short As[2][256 * 64];
  __shared__ __align__(16) unsigned short Bs[2][192 * 64];

  const int tid = threadIdx.x, lane = tid & 63, w = tid >> 6;
  const int n0 = blockIdx.x * 192, m0 = blockIdx.y * 256;
  const int wm = (w >> 2) * 128, wn = (w & 3) * 48;
  const int rowq = lane & 15, klane = lane >> 4;
  const int sw  = (rowq & 7) << 4;
  const int cb0 = (klane * 16) ^ sw;          // ks=0 (slots 0..3)
  const int cb1 = ((klane + 4) * 16) ^ sw;    // ks=1 (slots 4..7)
  const int srow = tid >> 3;                  // 0..63
  const int dc8  = (tid & 7) * 8;             // linear lds col (elements)
  const int scol = (((tid & 7) * 16) ^ ((srow & 7) << 4)) >> 1;  // global col (elems)

  const unsigned short* Ag = A  + (size_t)(m0 + srow) * K + scol;
  const unsigned short* Bg = Bw + (size_t)(n0 + srow) * K + scol;

  f32x4 acc[8][3];
#pragma unroll
  for (int i = 0; i < 8; ++i)
#pragma unroll
    for (int j = 0; j < 3; ++j)
#pragma unroll
      for (int r = 0; r < 4; ++r) acc[i][j][r] = 0.f;

  bf16x8 af[2][2], bfr[3][2];

  {
    unsigned short* Al = (unsigned short*)&As[0][0] + srow * 64 + dc8;
    unsigned short* Bl = (unsigned short*)&Bs[0][0] + srow * 64 + dc8;
    QKV_STG(Bg, Bl, 0); QKV_STG(Bg, Bl, 64); QKV_STG(Bg, Bl, 128);
    QKV_STG(Ag, Al, 0); QKV_STG(Ag, Al, 128);
    QKV_STG(Ag, Al, 64); QKV_STG(Ag, Al, 192);
  }
  QKV_VMC2;   // oldest 5 (B0,B1,B2,A0,A2) landed
  QKV_BAR;

  const unsigned short* Acur = &As[0][0];
  const unsigned short* Bcur = &Bs[0][0];
  unsigned short* Anx = (unsigned short*)&As[1][0];
  unsigned short* Bnx = (unsigned short*)&Bs[1][0];

  for (int t = 0; t < NT - 1; ++t) {
    const int kn = (t + 1) * 64;
    const unsigned short* Agk = Ag + kn;
    const unsigned short* Bgk = Bg + kn;
    unsigned short* Al = Anx + srow * 64 + dc8;
    unsigned short* Bl = Bnx + srow * 64 + dc8;

    QKV_LOADA(0); QKV_LOADB();
    QKV_STG(Bgk, Bl, 0); QKV_STG(Bgk, Bl, 64);
    QKV_BAR;
    __builtin_amdgcn_s_setprio(1); QKV_MFMA(0); __builtin_amdgcn_s_setprio(0);
    QKV_BAR;
    QKV_LOADA(1);
    QKV_STG(Bgk, Bl, 128); QKV_STG(Agk, Al, 0);
    QKV_BAR;
    __builtin_amdgcn_s_setprio(1); QKV_MFMA(1); __builtin_amdgcn_s_setprio(0);
    QKV_VMC4;
    QKV_BAR;
    QKV_LOADA(2);
    QKV_STG(Agk, Al, 128); QKV_STG(Agk, Al, 64);
    QKV_BAR;
    __builtin_amdgcn_s_setprio(1); QKV_MFMA(2); __builtin_amdgcn_s_setprio(0);
    QKV_BAR;
    QKV_LOADA(3);
    QKV_STG(Agk, Al, 192);
    QKV_BAR;
    __builtin_amdgcn_s_setprio(1); QKV_MFMA(3); __builtin_amdgcn_s_setprio(0);
    QKV_VMC2;
    QKV_BAR;

    { const unsigned short* tp = Acur; Acur = Anx; Anx = (unsigned short*)tp; }
    { const unsigned short* tp = Bcur; Bcur = Bnx; Bnx = (unsigned short*)tp; }
  }

  QKV_LOADA(0); QKV_LOADB();
  QKV_BAR;
  __builtin_amdgcn_s_setprio(1); QKV_MFMA(0); __builtin_amdgcn_s_setprio(0);
  QKV_BAR;
  QKV_LOADA(1);
  QKV_BAR;
  __builtin_amdgcn_s_setprio(1); QKV_MFMA(1); __builtin_amdgcn_s_setprio(0);
  QKV_VMC0;
  QKV_BAR;
  QKV_LOADA(2);
  QKV_BAR;
  __builtin_amdgcn_s_setprio(1); QKV_MFMA(2); __builtin_amdgcn_s_setprio(0);
  QKV_BAR;
  QKV_LOADA(3);
  __builtin_amdgcn_s_setprio(1); QKV_MFMA(3); __builtin_amdgcn_s_setprio(0);

  const int lr0 = klane * 4;
#pragma unroll
  for (int mi = 0; mi < 8; ++mi)
#pragma unroll
    for (int ni = 0; ni < 3; ++ni)
#pragma unroll
      for (int r = 0; r < 4; ++r) {
        int r_ = m0 + wm + mi * 16 + lr0 + r;
        int c_ = n0 + wn + ni * 16 + rowq;
        float v = acc[mi][ni][r];
        int b = r_ >> 11, s = r_ & 2047;
        int proj = c_ >> 11, cin = c_ & 2047;
        if (proj == 2) {
          Vtmp[(size_t)(b * S_ + s) * HID_ + cin] = f2bf(v);
        } else {
          int hh = cin >> 7, d = cin & 127;
          unsigned short* dst = (proj == 0) ? Qb : Kb;
          dst[(((size_t)(b * NH_ + hh) * S_ + s) * HD_) + d] = f2bf(v);
        }
      }
}

// ---------------- output projection: 256x128 tile, BK=64, 4-phase/K-tile ----------------
#define OUT_LOADA(Q) do { \
  _Pragma("unroll") \
  for (int mi_ = 0; mi_ < 2; ++mi_) { \
    const char* rp_ = (const char*)Acur + (size_t)((wm + (Q) * 32 + mi_ * 16 + rowq) * 128); \
    af[mi_][0] = *(const bf16x8*)(rp_ + cb0); \
    af[mi_][1] = *(const bf16x8*)(rp_ + cb1); \
  } } while (0)

#define OUT_LOADB() do { \
  _Pragma("unroll") \
  for (int ni_ = 0; ni_ < 2; ++ni_) { \
    const char* rp_ = (const char*)Bcur + (size_t)((wn + ni_ * 16 + rowq) * 128); \
    bfr[ni_][0] = *(const bf16x8*)(rp_ + cb0); \
    bfr[ni_][1] = *(const bf16x8*)(rp_ + cb1); \
  } } while (0)

#define OUT_MFMA(Q) do { \
  _Pragma("unroll") \
  for (int mi_ = 0; mi_ < 2; ++mi_) { \
    _Pragma("unroll") \
    for (int ni_ = 0; ni_ < 2; ++ni_) { \
      f32x4 c_ = acc[(Q) * 2 + mi_][ni_]; \
      c_ = __builtin_amdgcn_mfma_f32_16x16x32_bf16(af[mi_][0], bfr[ni_][0], c_, 0, 0, 0); \
      c_ = __builtin_amdgcn_mfma_f32_16x16x32_bf16(af[mi_][1], bfr[ni_][1], c_, 0, 0, 0); \
      acc[(Q) * 2 + mi_][ni_] = c_; \
    } } } while (0)

__global__ __launch_bounds__(512, 2)
void gemm_out(const unsigned short* __restrict__ A,
              const unsigned short* __restrict__ Bw,
              float* __restrict__ Cout) {
  const int K = HID_, N = HID_;
  const int NT = K / 64;    // 32
  __shared__ __align__(16) unsigned short As[2][256 * 64];
  __shared__ __align__(16) unsigned short Bs[2][128 * 64];

  const int tid = threadIdx.x, lane = tid & 63, w = tid >> 6;
  const int n0 = blockIdx.x * 128, m0 = blockIdx.y * 256;
  const int wm = (w >> 2) * 128, wn = (w & 3) * 32;
  const int rowq = lane & 15, klane = lane >> 4;
  const int sw  = (rowq & 7) << 4;
  const int cb0 = (klane * 16) ^ sw;
  const int cb1 = ((klane + 4) * 16) ^ sw;
  const int srow = tid >> 3;
  const int dc8  = (tid & 7) * 8;
  const int scol = (((tid & 7) * 16) ^ ((srow & 7) << 4)) >> 1;

  const unsigned short* Ag = A  + (size_t)(m0 + srow) * K + scol;
  const unsigned short* Bg = Bw + (size_t)(n0 + srow) * K + scol;

  f32x4 acc[8][2];
#pragma unroll
  for (int i = 0; i < 8; ++i)
#pragma unroll
    for (int j = 0; j < 2; ++j)
#pragma unroll
      for (int r = 0; r < 4; ++r) acc[i][j][r] = 0.f;

  bf16x8 af[2][2], bfr[2][2];

  {
    unsigned short* Al = (unsigned short*)&As[0][0] + srow * 64 + dc8;
    unsigned short* Bl = (unsigned short*)&Bs[0][0] + srow * 64 + dc8;
    QKV_STG(Bg, Bl, 0); QKV_STG(Bg, Bl, 64);
    QKV_STG(Ag, Al, 0); QKV_STG(Ag, Al, 128);
    QKV_STG(Ag, Al, 64); QKV_STG(Ag, Al, 192);
  }
  QKV_VMC2;   // oldest 4 (B0,B1,A0,A2) landed
  QKV_BAR;

  const unsigned short* Acur = &As[0][0];
  const unsigned short* Bcur = &Bs[0][0];
  unsigned short* Anx = (unsigned short*)&As[1][0];
  unsigned short* Bnx = (unsigned short*)&Bs[1][0];

  for (int t = 0; t < NT - 1; ++t) {
    const int kn = (t + 1) * 64;
    const unsigned short* Agk = Ag + kn;
    const unsigned short* Bgk = Bg + kn;
    unsigned short* Al = Anx + srow * 64 + dc8;
    unsigned short* Bl = Bnx + srow * 64 + dc8;

    OUT_LOADA(0); OUT_LOADB();
    QKV_STG(Bgk, Bl, 0); QKV_STG(Bgk, Bl, 64);
    QKV_BAR;
    __builtin_amdgcn_s_setprio(1); OUT_MFMA(0); __builtin_amdgcn_s_setprio(0);
    QKV_BAR;
    OUT_LOADA(1);
    QKV_STG(Agk, Al, 0); QKV_STG(Agk, Al, 128);
    QKV_BAR;
    __builtin_amdgcn_s_setprio(1); OUT_MFMA(1); __builtin_amdgcn_s_setprio(0);
    QKV_VMC4;
    QKV_BAR;
    OUT_LOADA(2);
    QKV_STG(Agk, Al, 64);
    QKV_BAR;
    __builtin_amdgcn_s_setprio(1); OUT_MFMA(2); __builtin_amdgcn_s_setprio(0);
    QKV_BAR;
    OUT_LOADA(3);
    QKV_STG(Agk, Al, 192);
    QKV_BAR;
    __builtin_amdgcn_s_setprio(1); OUT_MFMA(3); __builtin_amdgcn_s_setprio(0);
    QKV_VMC2;
    QKV_BAR;

    { const unsigned short* tp = Acur; Acur = Anx; Anx = (unsigned short*)tp; }
    { const unsigned short* tp = Bcur; Bcur = Bnx; Bnx = (unsigned short*)tp; }
  }

  OUT_LOADA(0); OUT_LOADB();
  QKV_BAR;
  __builtin_amdgcn_s_setprio(1); OUT_MFMA(0); __builtin_amdgcn_s_setprio(0);
  QKV_BAR;
  OUT_LOADA(1);
  QKV_BAR;
  __builtin_amdgcn_s_setprio(1); OUT_MFMA(1); __builtin_amdgcn_s_setprio(0);
  QKV_VMC0;
  QKV_BAR;
  OUT_LOADA(2);
  QKV_BAR;
  __builtin_amdgcn_s_setprio(1); OUT_MFMA(2); __builtin_amdgcn_s_setprio(0);
  QKV_BAR;
  OUT_LOADA(3);
  __builtin_amdgcn_s_setprio(1); OUT_MFMA(3); __builtin_amdgcn_s_setprio(0);

  const int lr0 = klane * 4;
#pragma unroll
  for (int mi = 0; mi < 8; ++mi)
#pragma unroll
    for (int ni = 0; ni < 2; ++ni)
#pragma unroll
      for (int r = 0; r < 4; ++r) {
        int r_ = m0 + wm + mi * 16 + lr0 + r;
        int c_ = n0 + wn + ni * 16 + rowq;
        Cout[(size_t)r_ * N + c_] = acc[mi][ni][r];
      }
}

// ---------------- RoPE: table precompute + vectorized apply ----------------
__global__ void rope_table(float2* __restrict__ tbl) {
  int i = blockIdx.x * blockDim.x + threadIdx.x;  // p*64 + d
  if (i >= MAXTOK_ * 64) return;
  int p = i >> 6, d = i & 63;
  float f = __expf(-(float)d * (9.210340371976184f / 64.f));  // 10000^(-d/64)
  float sn, cs;
  __sincosf((float)p * f, &sn, &cs);
  tbl[i] = make_float2(cs, sn);
}

#define QSCALE_ 0.12751744f
__global__ __launch_bounds__(256)
void rope_apply(unsigned short* __restrict__ Qb, unsigned short* __restrict__ Kb,
                const int* __restrict__ pos_ids, const float2* __restrict__ tbl) {
  int i = blockIdx.x * blockDim.x + threadIdx.x;  // bhs*8 + t8
  int t8 = i & 7, bhs = i >> 3;
  int s = bhs & (S_ - 1);
  int b = bhs >> 15;  // NH_*S_ = 32768
  int d0 = t8 * 8;
  int p = pos_ids[b * S_ + s];
  const float2* tp = tbl + p * 64 + d0;
  float cs[8], sn[8];
#pragma unroll
  for (int j = 0; j < 8; ++j) { float2 c2 = tp[j]; cs[j] = c2.x; sn[j] = c2.y; }
  size_t base = (size_t)bhs * HD_ + d0;
  {
    u16x8 x1 = *(const u16x8*)(Qb + base);
    u16x8 x2 = *(const u16x8*)(Qb + base + 64);
    u16x8 o1, o2;
#pragma unroll
    for (int j = 0; j < 8; ++j) {
      float a = bf2f(x1[j]), bb = bf2f(x2[j]);
      o1[j] = f2bf((a * cs[j] - bb * sn[j]) * QSCALE_);
      o2[j] = f2bf((bb * cs[j] + a * sn[j]) * QSCALE_);
    }
    *(u16x8*)(Qb + base) = o1;
    *(u16x8*)(Qb + base + 64) = o2;
  }
  {
    u16x8 x1 = *(const u16x8*)(Kb + base);
    u16x8 x2 = *(const u16x8*)(Kb + base + 64);
    u16x8 o1, o2;
#pragma unroll
    for (int j = 0; j < 8; ++j) {
      float a = bf2f(x1[j]), bb = bf2f(x2[j]);
      o1[j] = f2bf(a * cs[j] - bb * sn[j]);
      o2[j] = f2bf(bb * cs[j] + a * sn[j]);
    }
    *(u16x8*)(Kb + base) = o1;
    *(u16x8*)(Kb + base + 64) = o2;
  }
}

// ---------------- transpose V: (B,S,HID) bf16 -> (B,NH,HD,S) bf16 ----------------
__global__ __launch_bounds__(256)
void transpose_v(const unsigned short* __restrict__ Vin,
                 unsigned short* __restrict__ Vt) {
  __shared__ __align__(16) unsigned short t[64 * 72];
  const int s0 = blockIdx.x * 64, d0 = blockIdx.y * 64, bh = blockIdx.z;
  const int b = bh >> 4, h = bh & 15;
  const int tid = threadIdx.x;
#pragma unroll
  for (int it = 0; it < 2; ++it) {
    int chunk = it * 256 + tid;          // 512 chunks of 8 elems
    int sl = chunk >> 3, dc = (chunk & 7) * 8;
    u16x8 v = *(const u16x8*)&Vin[(size_t)(b * S_ + s0 + sl) * HID_ + h * HD_ + d0 + dc];
    *(u16x8*)&t[sl * 72 + dc] = v;
  }
  __syncthreads();
#pragma unroll
  for (int it = 0; it < 2; ++it) {
    int lin = it * 256 + tid;
    int dl = lin & 63, sq = (lin >> 6) * 8;  // lanes span dl -> banks spread
    u16x8 v;
#pragma unroll
    for (int j = 0; j < 8; ++j) v[j] = t[(sq + j) * 72 + dl];
    *(u16x8*)&Vt[((size_t)bh * HD_ + d0 + dl) * S_ + s0 + sq] = v;
  }
}

// ---------------- fused causal flash attention (v7) ----------------
// QBLK 128, 512 threads / 8 waves, grid (32,16) = 512 blocks at 2/CU = 1 round;
// complementary qt pairing (qtv = qtb<8 ? 15-qtb : qtb-8) balances per-CU work.
// K/V staged via global_load_lds with the verified swizzle (linear LDS dst +
// inverse-swizzled global source col; read col slot ^= row&7).
// K double-buffered with counted vmcnt (never drains mid-loop):
//   per tile: bar; issue V(kt)+K(kt+1); vmcnt(4); bar; QK^T+softmax;
//             vmcnt(2); bar; P->LDS->PV.
#define PS_LD 72
__global__ __launch_bounds__(512, 4)
void attn_fused(const unsigned short* __restrict__ Qb,
                const unsigned short* __restrict__ Kb,
                const unsigned short* __restrict__ Vt,
                unsigned short* __restrict__ Ob) {
  __shared__ __align__(16) unsigned short Ks[2][64 * 128];  // swizzled content
  __shared__ __align__(16) unsigned short Vts[128 * 64];    // swizzled content
  __shared__ __align__(16) unsigned short Ps[8 * 16 * PS_LD];

  const int tid = threadIdx.x, lane = tid & 63, w = tid >> 6;  // w 0..7
  const int bh = blockIdx.x;
  const int qtb = blockIdx.y;
  const int qtv = (qtb < 8) ? (15 - qtb) : (qtb - 8);  // pairing remap
  const int q0 = qtv * 128;
  const int b = bh >> 4, h = bh & 15;
  const int rowq = lane & 15, klane = lane >> 4;
  const int koff = klane * 8;
  const int lr0 = klane * 4;
  const size_t qkbase = (size_t)bh * (S_ * HD_);
  const size_t vbase  = (size_t)bh * (HD_ * S_);

  // swizzled read byte-offsets: slot' = slot ^ (row&7); row&7 == rowq&7
  int cbK0 = ((0 * 4 + klane) ^ (rowq & 7)) << 4;
  int cbK1 = ((1 * 4 + klane) ^ (rowq & 7)) << 4;
  int cbK2 = ((2 * 4 + klane) ^ (rowq & 7)) << 4;
  int cbK3 = ((3 * 4 + klane) ^ (rowq & 7)) << 4;

  // Q fragments in regs (16 rows per wave)
  bf16x8 qf0, qf1, qf2, qf3;
  {
    const unsigned short* qrow = Qb + qkbase + (size_t)(q0 + w * 16 + rowq) * HD_;
    qf0 = *(const bf16x8*)(qrow + 0 * 32 + koff);
    qf1 = *(const bf16x8*)(qrow + 1 * 32 + koff);
    qf2 = *(const bf16x8*)(qrow + 2 * 32 + koff);
    qf3 = *(const bf16x8*)(qrow + 3 * 32 + koff);
  }

  // staging decomposition (512 threads x 16B)
  // K tile 64x128 (256B rows, slots 0..15): 2 calls of 32 rows
  const int krl = tid >> 4;                 // 0..31
  const int ksl = tid & 15;
  const int scolK = ((ksl ^ (krl & 7)) * 8);   // inverse-swizzled global col
  const unsigned short* Kg = Kb + qkbase + (size_t)krl * HD_ + scolK;
  unsigned short* Kdst = (unsigned short*)Ks + krl * 128 + ksl * 8;
  // V^T tile 128x64 (128B rows, slots 0..7): 2 calls of 64 rows
  const int vrl = tid >> 3;                 // 0..63
  const int vsl = tid & 7;
  const int scolV = ((vsl ^ (vrl & 7)) * 8);
  const unsigned short* Vg = Vt + vbase + (size_t)vrl * S_ + scolV;
  unsigned short* Vdst = (unsigned short*)Vts + vrl * 64 + vsl * 8;

#define ATT_STAGE_K(KT, BUF) do { \
  gload16(Kg + (size_t)((KT) * 64) * HD_,      Kdst + (BUF) * (64 * 128)); \
  gload16(Kg + (size_t)((KT) * 64 + 32) * HD_, Kdst + (BUF) * (64 * 128) + 32 * 128); \
} while (0)
#define ATT_STAGE_V(KT) do { \
  gload16(Vg + (KT) * 64,                   Vdst); \
  gload16(Vg + (size_t)64 * S_ + (KT) * 64, Vdst + 64 * 64); \
} while (0)

  f32x4 oacc[8];
#pragma unroll
  for (int i = 0; i < 8; ++i)
#pragma unroll
    for (int r = 0; r < 4; ++r) oacc[i][r] = 0.f;
  float m_r[4] = {-3e38f, -3e38f, -3e38f, -3e38f};
  float l_r[4] = {0.f, 0.f, 0.f, 0.f};

  const int nkt = 2 * qtv + 2;
  int cur = 0;

  ATT_STAGE_K(0, 0);   // prologue: K(0) -> Ks[0]; 2 outstanding

  for (int kt = 0; kt < nkt; ++kt) {
    __syncthreads();   // prev tile's Vts/Ks[nxt] readers done
    ATT_STAGE_V(kt);
    const bool hn = (kt + 1 < nkt);
    if (hn) {
      ATT_STAGE_K(kt + 1, cur ^ 1);
      asm volatile("s_waitcnt vmcnt(4)" ::: "memory");  // K(kt)'s 2 landed
    } else {
      asm volatile("s_waitcnt vmcnt(2)" ::: "memory");
    }
    __syncthreads();   // all waves' K(kt) parts visible

    // S = Q K^T (pre-scaled by scale*log2e via Q)
    const unsigned short* Kc = (const unsigned short*)Ks + cur * (64 * 128);
    f32x4 sacc[4];
#pragma unroll
    for (int n = 0; n < 4; ++n)
#pragma unroll
      for (int r = 0; r < 4; ++r) sacc[n][r] = 0.f;
#pragma unroll
    for (int n = 0; n < 4; ++n) {
      const char* rp = (const char*)(Kc + (n * 16 + rowq) * 128);
      sacc[n] = __builtin_amdgcn_mfma_f32_16x16x32_bf16(qf0, *(const bf16x8*)(rp + cbK0), sacc[n], 0, 0, 0);
      sacc[n] = __builtin_amdgcn_mfma_f32_16x16x32_bf16(qf1, *(const bf16x8*)(rp + cbK1), sacc[n], 0, 0, 0);
      sacc[n] = __builtin_amdgcn_mfma_f32_16x16x32_bf16(qf2, *(const bf16x8*)(rp + cbK2), sacc[n], 0, 0, 0);
      sacc[n] = __builtin_amdgcn_mfma_f32_16x16x32_bf16(qf3, *(const bf16x8*)(rp + cbK3), sacc[n], 0, 0, 0);
    }

    // causal mask (only tiles overlapping the diagonal) + online softmax
    float tmax[4] = {-3e38f, -3e38f, -3e38f, -3e38f};
    if (kt >= 2 * qtv) {
      const int cbase = (kt - 2 * qtv) * 64;
#pragma unroll
      for (int n = 0; n < 4; ++n) {
        int coll = cbase + n * 16 + rowq;
#pragma unroll
        for (int r = 0; r < 4; ++r) {
          int rowl = w * 16 + lr0 + r;
          float x = (coll <= rowl) ? sacc[n][r] : -1e30f;
          sacc[n][r] = x;
          tmax[r] = fmaxf(tmax[r], x);
        }
      }
    } else {
#pragma unroll
      for (int n = 0; n < 4; ++n)
#pragma unroll
        for (int r = 0; r < 4; ++r)
          tmax[r] = fmaxf(tmax[r], sacc[n][r]);
    }
#pragma unroll
    for (int off = 1; off < 16; off <<= 1)
#pragma unroll
      for (int r = 0; r < 4; ++r) tmax[r] = fmaxf(tmax[r], __shfl_xor(tmax[r], off));
    float alpha[4];
#pragma unroll
    for (int r = 0; r < 4; ++r) {
      float mn = fmaxf(m_r[r], tmax[r]);
      alpha[r] = __builtin_amdgcn_exp2f(m_r[r] - mn);
      m_r[r] = mn;
    }
    float rs[4] = {0.f, 0.f, 0.f, 0.f};
#pragma unroll
    for (int n = 0; n < 4; ++n)
#pragma unroll
      for (int r = 0; r < 4; ++r) {
        float p = __builtin_amdgcn_exp2f(sacc[n][r] - m_r[r]);
        sacc[n][r] = p;
        rs[r] += p;
      }
#pragma unroll
    for (int off = 1; off < 16; off <<= 1)
#pragma unroll
      for (int r = 0; r < 4; ++r) rs[r] += __shfl_xor(rs[r], off);
#pragma unroll
    for (int r = 0; r < 4; ++r) l_r[r] = l_r[r] * alpha[r] + rs[r];
#pragma unroll
    for (int nd = 0; nd < 8; ++nd)
#pragma unroll
      for (int r = 0; r < 4; ++r) oacc[nd][r] *= alpha[r];

    if (hn) { asm volatile("s_waitcnt vmcnt(2)" ::: "memory"); }  // V(kt) landed
    else    { asm volatile("s_waitcnt vmcnt(0)" ::: "memory"); }
    __syncthreads();   // all waves' V parts visible

    // P: C-layout -> LDS (wave-private) -> A-layout
    unsigned short* pw = &Ps[w * 16 * PS_LD];
#pragma unroll
    for (int n = 0; n < 4; ++n)
#pragma unroll
      for (int r = 0; r < 4; ++r)
        pw[(lr0 + r) * PS_LD + n * 16 + rowq] = f2bf(sacc[n][r]);

    // O += P V  (V^T frags swizzle-read)
#pragma unroll
    for (int t2 = 0; t2 < 2; ++t2) {
      bf16x8 pa = *(const bf16x8*)&pw[rowq * PS_LD + t2 * 32 + koff];
      const int cbv = ((t2 * 4 + klane) ^ (rowq & 7)) << 4;
#pragma unroll
      for (int nd = 0; nd < 8; ++nd) {
        const char* vp = (const char*)((const unsigned short*)Vts + (nd * 16 + rowq) * 64);
        bf16x8 vb = *(const bf16x8*)(vp + cbv);
        oacc[nd] = __builtin_amdgcn_mfma_f32_16x16x32_bf16(pa, vb, oacc[nd], 0, 0, 0);
      }
    }
    cur ^= 1;
  }

  // epilogue: multiply by 1/l, store bf16 to (B,S,HID)
  float linv[4];
#pragma unroll
  for (int r = 0; r < 4; ++r) linv[r] = __builtin_amdgcn_rcpf(l_r[r]);
#pragma unroll
  for (int nd = 0; nd < 8; ++nd) {
    int col = h * HD_ + nd * 16 + rowq;
#pragma unroll
    for (int r = 0; r < 4; ++r) {
      int row = q0 + w * 16 + lr0 + r;
      Ob[(size_t)(b * S_ + row) * HID_ + col] = f2bf(oacc[nd][r] * linv[r]);
    }
  }
}

// ---------------- launcher ----------------
extern "C" void kernel_launch(void* const* d_in, const int* in_sizes, int n_in,
                              void* d_out, int out_size, void* d_ws, size_t ws_size,
                              hipStream_t stream) {
  (void)in_sizes; (void)n_in; (void)out_size; (void)ws_size;
  const float* hidden = (const float*)d_in[0];
  // d_in[1] = attention_mask (causal; reproduced analytically)
  const int* pos = (const int*)d_in[2];
  const float* Wq = (const float*)d_in[3];
  const float* Wk = (const float*)d_in[4];
  const float* Wv = (const float*)d_in[5];
  const float* Wo = (const float*)d_in[6];
  float* out = (float*)d_out;

  char* ws = (char*)d_ws;
  unsigned short* Xb   = (unsigned short*)(ws);               // 16 MB  (B,S,HID) bf16
  unsigned short* Wqb  = (unsigned short*)(ws + 16777216);    // 8 MB  Wq -- Wqb/Wkb/Wvb contiguous:
  unsigned short* Wkb  = (unsigned short*)(ws + 25165824);    // 8 MB  Wk -- one (6144,2048) QKV weight
  unsigned short* Wvb  = (unsigned short*)(ws + 33554432);    // 8 MB  Wv
  unsigned short* Wob  = (unsigned short*)(ws + 41943040);    // 8 MB
  unsigned short* Qb   = (unsigned short*)(ws + 50331648);    // 16 MB (B,NH,S,HD)
  unsigned short* Kb   = (unsigned short*)(ws + 67108864);    // 16 MB
  unsigned short* Vtmp = (unsigned short*)(ws + 83886080);    // 16 MB (B,S,HID)
  unsigned short* Vtb  = (unsigned short*)(ws + 100663296);   // 16 MB (B,NH,HD,S)
  unsigned short* Ob   = Xb;          // Xb dead after QKV GEMM
  float2* tbl          = (float2*)ws; // RoPE table also lives in dead Xb region (1 MB)

  cast_all<<<2048, 256, 0, stream>>>(hidden, Wq, Wk, Wv, Wo, Xb, Wqb, Wkb, Wvb, Wob);

  // fused QKV: C (4096 x 6144) = X (4096x2048) * Wqkv^T, 256x192 tiles
  dim3 gq(3 * HID_ / 192, (B_ * S_) / 256);  // (32, 16) = 512 blocks = exactly 2 rounds
  gemm_qkv<<<gq, 512, 0, stream>>>(Xb, Wqb, Qb, Kb, Vtmp);

  rope_table<<<(MAXTOK_ * 64) / 256, 256, 0, stream>>>(tbl);
  rope_apply<<<(B_ * NH_ * S_ * 8) / 256, 256, 0, stream>>>(Qb, Kb, pos, tbl);

  dim3 tg(S_ / 64, HD_ / 64, B_ * NH_);  // (32, 2, 32)
  transpose_v<<<tg, 256, 0, stream>>>(Vtmp, Vtb);

  dim3 ag(B_ * NH_, S_ / 128);  // (32, 16) = 512 blocks at 2/CU = exactly 1 round
  attn_fused<<<ag, 512, 0, stream>>>(Qb, Kb, Vtb, Ob);

  dim3 go(HID_ / 128, (B_ * S_) / 256);  // (16, 16) = 256 blocks = exactly 1 round
  gemm_out<<<go, 512, 0, stream>>>(Ob, Wob, out);
}

// Round 8
// 397.174 us; speedup vs baseline: 1.0422x; 1.0422x over previous
//
#include <hip/hip_runtime.h>

#define B_   2
#define S_   2048
#define HID_ 2048
#define NH_  16
#define HD_  128
#define MAXTOK_ 2048

typedef float  f32x4  __attribute__((ext_vector_type(4)));
typedef __bf16 bf16x8 __attribute__((ext_vector_type(8)));
typedef unsigned short u16x8 __attribute__((ext_vector_type(8)));

__device__ __forceinline__ unsigned short f2bf(float f) {
  union { float fv; unsigned u; } v; v.fv = f;
  unsigned r = v.u + 0x7FFFu + ((v.u >> 16) & 1u);  // RNE
  return (unsigned short)(r >> 16);
}
__device__ __forceinline__ float bf2f(unsigned short h) {
  union { unsigned u; float fv; } v; v.u = ((unsigned)h) << 16;
  return v.fv;
}

// async global->LDS, 16B per lane (LDS dst must be linear/contiguous)
__device__ __forceinline__ void gload16(const void* g, void* lds) {
  __builtin_amdgcn_global_load_lds(
      (const __attribute__((address_space(1))) void*)g,
      (__attribute__((address_space(3))) void*)lds, 16, 0, 0);
}

// ---------------- fused cast fp32 -> bf16 for hidden + 4 weights ----------------
#define H4_ (B_ * S_ * HID_ / 4)
#define W4_ (HID_ * HID_ / 4)
__global__ void cast_all(const float* __restrict__ h,  const float* __restrict__ wq,
                         const float* __restrict__ wk, const float* __restrict__ wv,
                         const float* __restrict__ wo,
                         unsigned short* __restrict__ xb,  unsigned short* __restrict__ wqb,
                         unsigned short* __restrict__ wkb, unsigned short* __restrict__ wvb,
                         unsigned short* __restrict__ wob) {
  const int total = H4_ + 4 * W4_;
  int i = blockIdx.x * blockDim.x + threadIdx.x;
  int stride = gridDim.x * blockDim.x;
  for (; i < total; i += stride) {
    const float* src; unsigned short* dst; int j;
    if (i < H4_) { src = h; dst = xb; j = i; }
    else {
      int k = i - H4_, wsel = k >> 20;  // W4_ = 2^20
      j = k & (W4_ - 1);
      src = (wsel == 0) ? wq : (wsel == 1) ? wk : (wsel == 2) ? wv : wo;
      dst = (wsel == 0) ? wqb : (wsel == 1) ? wkb : (wsel == 2) ? wvb : wob;
    }
    float4 v = ((const float4*)src)[j];
    ushort4 o;
    o.x = f2bf(v.x); o.y = f2bf(v.y); o.z = f2bf(v.z); o.w = f2bf(v.w);
    ((ushort4*)dst)[j] = o;
  }
}

// ---------------- fused QKV projection: 256x192 tile, BK=64, 4-phase/K-tile ----------------
// Round-3 verified structure (107 us, MfmaUtil 40%, conflicts 0). UNCHANGED.
#define QKV_STG(gp, lp, rb) gload16((gp) + (size_t)(rb) * 2048, (lp) + (rb) * 64)

#define QKV_LOADA(Q) do { \
  _Pragma("unroll") \
  for (int mi_ = 0; mi_ < 2; ++mi_) { \
    const char* rp_ = (const char*)Acur + (size_t)((wm + (Q) * 32 + mi_ * 16 + rowq) * 128); \
    af[mi_][0] = *(const bf16x8*)(rp_ + cb0); \
    af[mi_][1] = *(const bf16x8*)(rp_ + cb1); \
  } } while (0)

#define QKV_LOADB() do { \
  _Pragma("unroll") \
  for (int ni_ = 0; ni_ < 3; ++ni_) { \
    const char* rp_ = (const char*)Bcur + (size_t)((wn + ni_ * 16 + rowq) * 128); \
    bfr[ni_][0] = *(const bf16x8*)(rp_ + cb0); \
    bfr[ni_][1] = *(const bf16x8*)(rp_ + cb1); \
  } } while (0)

#define QKV_MFMA(Q) do { \
  _Pragma("unroll") \
  for (int mi_ = 0; mi_ < 2; ++mi_) { \
    _Pragma("unroll") \
    for (int ni_ = 0; ni_ < 3; ++ni_) { \
      f32x4 c_ = acc[(Q) * 2 + mi_][ni_]; \
      c_ = __builtin_amdgcn_mfma_f32_16x16x32_bf16(af[mi_][0], bfr[ni_][0], c_, 0, 0, 0); \
      c_ = __builtin_amdgcn_mfma_f32_16x16x32_bf16(af[mi_][1], bfr[ni_][1], c_, 0, 0, 0); \
      acc[(Q) * 2 + mi_][ni_] = c_; \
    } } } while (0)

#define QKV_BAR    asm volatile("s_barrier" ::: "memory")
#define QKV_VMC4   asm volatile("s_waitcnt vmcnt(4)" ::: "memory")
#define QKV_VMC2   asm volatile("s_waitcnt vmcnt(2)" ::: "memory")
#define QKV_VMC0   asm volatile("s_waitcnt vmcnt(0)" ::: "memory")

__global__ __launch_bounds__(512, 2)
void gemm_qkv(const unsigned short* __restrict__ A,
              const unsigned short* __restrict__ Bw,
              unsigned short* __restrict__ Qb,
              unsigned short* __restrict__ Kb,
              unsigned short* __restrict__ Vtmp) {
  const int K = HID_;       // 2048
  const int NT = K / 64;    // 32 K-tiles
  __shared__ __align__(16) unsigned short As[2][256 * 64];
  __shared__ __align__(16) unsigned short Bs[2][192 * 64];

  const int tid = threadIdx.x, lane = tid & 63, w = tid >> 6;
  const int n0 = blockIdx.x * 192, m0 = blockIdx.y * 256;
  const int wm = (w >> 2) * 128, wn = (w & 3) * 48;
  const int rowq = lane & 15, klane = lane >> 4;
  const int sw  = (rowq & 7) << 4;
  const int cb0 = (klane * 16) ^ sw;          // ks=0 (slots 0..3)
  const int cb1 = ((klane + 4) * 16) ^ sw;    // ks=1 (slots 4..7)
  const int srow = tid >> 3;                  // 0..63
  const int dc8  = (tid & 7) * 8;             // linear lds col (elements)
  const int scol = (((tid & 7) * 16) ^ ((srow & 7) << 4)) >> 1;  // global col (elems)

  const unsigned short* Ag = A  + (size_t)(m0 + srow) * K + scol;
  const unsigned short* Bg = Bw + (size_t)(n0 + srow) * K + scol;

  f32x4 acc[8][3];
#pragma unroll
  for (int i = 0; i < 8; ++i)
#pragma unroll
    for (int j = 0; j < 3; ++j)
#pragma unroll
      for (int r = 0; r < 4; ++r) acc[i][j][r] = 0.f;

  bf16x8 af[2][2], bfr[3][2];

  {
    unsigned short* Al = (unsigned short*)&As[0][0] + srow * 64 + dc8;
    unsigned short* Bl = (unsigned short*)&Bs[0][0] + srow * 64 + dc8;
    QKV_STG(Bg, Bl, 0); QKV_STG(Bg, Bl, 64); QKV_STG(Bg, Bl, 128);
    QKV_STG(Ag, Al, 0); QKV_STG(Ag, Al, 128);
    QKV_STG(Ag, Al, 64); QKV_STG(Ag, Al, 192);
  }
  QKV_VMC2;   // oldest 5 (B0,B1,B2,A0,A2) landed
  QKV_BAR;

  const unsigned short* Acur = &As[0][0];
  const unsigned short* Bcur = &Bs[0][0];
  unsigned short* Anx = (unsigned short*)&As[1][0];
  unsigned short* Bnx = (unsigned short*)&Bs[1][0];

  for (int t = 0; t < NT - 1; ++t) {
    const int kn = (t + 1) * 64;
    const unsigned short* Agk = Ag + kn;
    const unsigned short* Bgk = Bg + kn;
    unsigned short* Al = Anx + srow * 64 + dc8;
    unsigned short* Bl = Bnx + srow * 64 + dc8;

    QKV_LOADA(0); QKV_LOADB();
    QKV_STG(Bgk, Bl, 0); QKV_STG(Bgk, Bl, 64);
    QKV_BAR;
    __builtin_amdgcn_s_setprio(1); QKV_MFMA(0); __builtin_amdgcn_s_setprio(0);
    QKV_BAR;
    QKV_LOADA(1);
    QKV_STG(Bgk, Bl, 128); QKV_STG(Agk, Al, 0);
    QKV_BAR;
    __builtin_amdgcn_s_setprio(1); QKV_MFMA(1); __builtin_amdgcn_s_setprio(0);
    QKV_VMC4;
    QKV_BAR;
    QKV_LOADA(2);
    QKV_STG(Agk, Al, 128); QKV_STG(Agk, Al, 64);
    QKV_BAR;
    __builtin_amdgcn_s_setprio(1); QKV_MFMA(2); __builtin_amdgcn_s_setprio(0);
    QKV_BAR;
    QKV_LOADA(3);
    QKV_STG(Agk, Al, 192);
    QKV_BAR;
    __builtin_amdgcn_s_setprio(1); QKV_MFMA(3); __builtin_amdgcn_s_setprio(0);
    QKV_VMC2;
    QKV_BAR;

    { const unsigned short* tp = Acur; Acur = Anx; Anx = (unsigned short*)tp; }
    { const unsigned short* tp = Bcur; Bcur = Bnx; Bnx = (unsigned short*)tp; }
  }

  QKV_LOADA(0); QKV_LOADB();
  QKV_BAR;
  __builtin_amdgcn_s_setprio(1); QKV_MFMA(0); __builtin_amdgcn_s_setprio(0);
  QKV_BAR;
  QKV_LOADA(1);
  QKV_BAR;
  __builtin_amdgcn_s_setprio(1); QKV_MFMA(1); __builtin_amdgcn_s_setprio(0);
  QKV_VMC0;
  QKV_BAR;
  QKV_LOADA(2);
  QKV_BAR;
  __builtin_amdgcn_s_setprio(1); QKV_MFMA(2); __builtin_amdgcn_s_setprio(0);
  QKV_BAR;
  QKV_LOADA(3);
  __builtin_amdgcn_s_setprio(1); QKV_MFMA(3); __builtin_amdgcn_s_setprio(0);

  const int lr0 = klane * 4;
#pragma unroll
  for (int mi = 0; mi < 8; ++mi)
#pragma unroll
    for (int ni = 0; ni < 3; ++ni)
#pragma unroll
      for (int r = 0; r < 4; ++r) {
        int r_ = m0 + wm + mi * 16 + lr0 + r;
        int c_ = n0 + wn + ni * 16 + rowq;
        float v = acc[mi][ni][r];
        int b = r_ >> 11, s = r_ & 2047;
        int proj = c_ >> 11, cin = c_ & 2047;
        if (proj == 2) {
          Vtmp[(size_t)(b * S_ + s) * HID_ + cin] = f2bf(v);
        } else {
          int hh = cin >> 7, d = cin & 127;
          unsigned short* dst = (proj == 0) ? Qb : Kb;
          dst[(((size_t)(b * NH_ + hh) * S_ + s) * HD_) + d] = f2bf(v);
        }
      }
}

// ---------------- output projection: 256x128 tile, BK=64, 4-phase/K-tile ----------------
#define OUT_LOADA(Q) do { \
  _Pragma("unroll") \
  for (int mi_ = 0; mi_ < 2; ++mi_) { \
    const char* rp_ = (const char*)Acur + (size_t)((wm + (Q) * 32 + mi_ * 16 + rowq) * 128); \
    af[mi_][0] = *(const bf16x8*)(rp_ + cb0); \
    af[mi_][1] = *(const bf16x8*)(rp_ + cb1); \
  } } while (0)

#define OUT_LOADB() do { \
  _Pragma("unroll") \
  for (int ni_ = 0; ni_ < 2; ++ni_) { \
    const char* rp_ = (const char*)Bcur + (size_t)((wn + ni_ * 16 + rowq) * 128); \
    bfr[ni_][0] = *(const bf16x8*)(rp_ + cb0); \
    bfr[ni_][1] = *(const bf16x8*)(rp_ + cb1); \
  } } while (0)

#define OUT_MFMA(Q) do { \
  _Pragma("unroll") \
  for (int mi_ = 0; mi_ < 2; ++mi_) { \
    _Pragma("unroll") \
    for (int ni_ = 0; ni_ < 2; ++ni_) { \
      f32x4 c_ = acc[(Q) * 2 + mi_][ni_]; \
      c_ = __builtin_amdgcn_mfma_f32_16x16x32_bf16(af[mi_][0], bfr[ni_][0], c_, 0, 0, 0); \
      c_ = __builtin_amdgcn_mfma_f32_16x16x32_bf16(af[mi_][1], bfr[ni_][1], c_, 0, 0, 0); \
      acc[(Q) * 2 + mi_][ni_] = c_; \
    } } } while (0)

__global__ __launch_bounds__(512, 2)
void gemm_out(const unsigned short* __restrict__ A,
              const unsigned short* __restrict__ Bw,
              float* __restrict__ Cout) {
  const int K = HID_, N = HID_;
  const int NT = K / 64;    // 32
  __shared__ __align__(16) unsigned short As[2][256 * 64];
  __shared__ __align__(16) unsigned short Bs[2][128 * 64];

  const int tid = threadIdx.x, lane = tid & 63, w = tid >> 6;
  const int n0 = blockIdx.x * 128, m0 = blockIdx.y * 256;
  const int wm = (w >> 2) * 128, wn = (w & 3) * 32;
  const int rowq = lane & 15, klane = lane >> 4;
  const int sw  = (rowq & 7) << 4;
  const int cb0 = (klane * 16) ^ sw;
  const int cb1 = ((klane + 4) * 16) ^ sw;
  const int srow = tid >> 3;
  const int dc8  = (tid & 7) * 8;
  const int scol = (((tid & 7) * 16) ^ ((srow & 7) << 4)) >> 1;

  const unsigned short* Ag = A  + (size_t)(m0 + srow) * K + scol;
  const unsigned short* Bg = Bw + (size_t)(n0 + srow) * K + scol;

  f32x4 acc[8][2];
#pragma unroll
  for (int i = 0; i < 8; ++i)
#pragma unroll
    for (int j = 0; j < 2; ++j)
#pragma unroll
      for (int r = 0; r < 4; ++r) acc[i][j][r] = 0.f;

  bf16x8 af[2][2], bfr[2][2];

  {
    unsigned short* Al = (unsigned short*)&As[0][0] + srow * 64 + dc8;
    unsigned short* Bl = (unsigned short*)&Bs[0][0] + srow * 64 + dc8;
    QKV_STG(Bg, Bl, 0); QKV_STG(Bg, Bl, 64);
    QKV_STG(Ag, Al, 0); QKV_STG(Ag, Al, 128);
    QKV_STG(Ag, Al, 64); QKV_STG(Ag, Al, 192);
  }
  QKV_VMC2;   // oldest 4 (B0,B1,A0,A2) landed
  QKV_BAR;

  const unsigned short* Acur = &As[0][0];
  const unsigned short* Bcur = &Bs[0][0];
  unsigned short* Anx = (unsigned short*)&As[1][0];
  unsigned short* Bnx = (unsigned short*)&Bs[1][0];

  for (int t = 0; t < NT - 1; ++t) {
    const int kn = (t + 1) * 64;
    const unsigned short* Agk = Ag + kn;
    const unsigned short* Bgk = Bg + kn;
    unsigned short* Al = Anx + srow * 64 + dc8;
    unsigned short* Bl = Bnx + srow * 64 + dc8;

    OUT_LOADA(0); OUT_LOADB();
    QKV_STG(Bgk, Bl, 0); QKV_STG(Bgk, Bl, 64);
    QKV_BAR;
    __builtin_amdgcn_s_setprio(1); OUT_MFMA(0); __builtin_amdgcn_s_setprio(0);
    QKV_BAR;
    OUT_LOADA(1);
    QKV_STG(Agk, Al, 0); QKV_STG(Agk, Al, 128);
    QKV_BAR;
    __builtin_amdgcn_s_setprio(1); OUT_MFMA(1); __builtin_amdgcn_s_setprio(0);
    QKV_VMC4;
    QKV_BAR;
    OUT_LOADA(2);
    QKV_STG(Agk, Al, 64);
    QKV_BAR;
    __builtin_amdgcn_s_setprio(1); OUT_MFMA(2); __builtin_amdgcn_s_setprio(0);
    QKV_BAR;
    OUT_LOADA(3);
    QKV_STG(Agk, Al, 192);
    QKV_BAR;
    __builtin_amdgcn_s_setprio(1); OUT_MFMA(3); __builtin_amdgcn_s_setprio(0);
    QKV_VMC2;
    QKV_BAR;

    { const unsigned short* tp = Acur; Acur = Anx; Anx = (unsigned short*)tp; }
    { const unsigned short* tp = Bcur; Bcur = Bnx; Bnx = (unsigned short*)tp; }
  }

  OUT_LOADA(0); OUT_LOADB();
  QKV_BAR;
  __builtin_amdgcn_s_setprio(1); OUT_MFMA(0); __builtin_amdgcn_s_setprio(0);
  QKV_BAR;
  OUT_LOADA(1);
  QKV_BAR;
  __builtin_amdgcn_s_setprio(1); OUT_MFMA(1); __builtin_amdgcn_s_setprio(0);
  QKV_VMC0;
  QKV_BAR;
  OUT_LOADA(2);
  QKV_BAR;
  __builtin_amdgcn_s_setprio(1); OUT_MFMA(2); __builtin_amdgcn_s_setprio(0);
  QKV_BAR;
  OUT_LOADA(3);
  __builtin_amdgcn_s_setprio(1); OUT_MFMA(3); __builtin_amdgcn_s_setprio(0);

  const int lr0 = klane * 4;
#pragma unroll
  for (int mi = 0; mi < 8; ++mi)
#pragma unroll
    for (int ni = 0; ni < 2; ++ni)
#pragma unroll
      for (int r = 0; r < 4; ++r) {
        int r_ = m0 + wm + mi * 16 + lr0 + r;
        int c_ = n0 + wn + ni * 16 + rowq;
        Cout[(size_t)r_ * N + c_] = acc[mi][ni][r];
      }
}

// ---------------- RoPE: table precompute + vectorized apply ----------------
__global__ void rope_table(float2* __restrict__ tbl) {
  int i = blockIdx.x * blockDim.x + threadIdx.x;  // p*64 + d
  if (i >= MAXTOK_ * 64) return;
  int p = i >> 6, d = i & 63;
  float f = __expf(-(float)d * (9.210340371976184f / 64.f));  // 10000^(-d/64)
  float sn, cs;
  __sincosf((float)p * f, &sn, &cs);
  tbl[i] = make_float2(cs, sn);
}

#define QSCALE_ 0.12751744f
__global__ __launch_bounds__(256)
void rope_apply(unsigned short* __restrict__ Qb, unsigned short* __restrict__ Kb,
                const int* __restrict__ pos_ids, const float2* __restrict__ tbl) {
  int i = blockIdx.x * blockDim.x + threadIdx.x;  // bhs*8 + t8
  int t8 = i & 7, bhs = i >> 3;
  int s = bhs & (S_ - 1);
  int b = bhs >> 15;  // NH_*S_ = 32768
  int d0 = t8 * 8;
  int p = pos_ids[b * S_ + s];
  const float2* tp = tbl + p * 64 + d0;
  float cs[8], sn[8];
#pragma unroll
  for (int j = 0; j < 8; ++j) { float2 c2 = tp[j]; cs[j] = c2.x; sn[j] = c2.y; }
  size_t base = (size_t)bhs * HD_ + d0;
  {
    u16x8 x1 = *(const u16x8*)(Qb + base);
    u16x8 x2 = *(const u16x8*)(Qb + base + 64);
    u16x8 o1, o2;
#pragma unroll
    for (int j = 0; j < 8; ++j) {
      float a = bf2f(x1[j]), bb = bf2f(x2[j]);
      o1[j] = f2bf((a * cs[j] - bb * sn[j]) * QSCALE_);
      o2[j] = f2bf((bb * cs[j] + a * sn[j]) * QSCALE_);
    }
    *(u16x8*)(Qb + base) = o1;
    *(u16x8*)(Qb + base + 64) = o2;
  }
  {
    u16x8 x1 = *(const u16x8*)(Kb + base);
    u16x8 x2 = *(const u16x8*)(Kb + base + 64);
    u16x8 o1, o2;
#pragma unroll
    for (int j = 0; j < 8; ++j) {
      float a = bf2f(x1[j]), bb = bf2f(x2[j]);
      o1[j] = f2bf(a * cs[j] - bb * sn[j]);
      o2[j] = f2bf(bb * cs[j] + a * sn[j]);
    }
    *(u16x8*)(Kb + base) = o1;
    *(u16x8*)(Kb + base + 64) = o2;
  }
}

// ---------------- transpose V: (B,S,HID) bf16 -> (B,NH,HD,S) bf16 ----------------
__global__ __launch_bounds__(256)
void transpose_v(const unsigned short* __restrict__ Vin,
                 unsigned short* __restrict__ Vt) {
  __shared__ __align__(16) unsigned short t[64 * 72];
  const int s0 = blockIdx.x * 64, d0 = blockIdx.y * 64, bh = blockIdx.z;
  const int b = bh >> 4, h = bh & 15;
  const int tid = threadIdx.x;
#pragma unroll
  for (int it = 0; it < 2; ++it) {
    int chunk = it * 256 + tid;          // 512 chunks of 8 elems
    int sl = chunk >> 3, dc = (chunk & 7) * 8;
    u16x8 v = *(const u16x8*)&Vin[(size_t)(b * S_ + s0 + sl) * HID_ + h * HD_ + d0 + dc];
    *(u16x8*)&t[sl * 72 + dc] = v;
  }
  __syncthreads();
#pragma unroll
  for (int it = 0; it < 2; ++it) {
    int lin = it * 256 + tid;
    int dl = lin & 63, sq = (lin >> 6) * 8;  // lanes span dl -> banks spread
    u16x8 v;
#pragma unroll
    for (int j = 0; j < 8; ++j) v[j] = t[(sq + j) * 72 + dl];
    *(u16x8*)&Vt[((size_t)bh * HD_ + d0 + dl) * S_ + s0 + sq] = v;
  }
}

// ---------------- fused causal flash attention (v6b) ----------------
// REVERTED to round-5 v6 (QBLK 64, 256 thr, 3 blocks/CU — the best-measured
// config; v7's QBLK-128 gload_lds pipeline was ~18 us SLOWER: fewer
// independent blocks + exposed V latency beat the staging savings).
// v6 -> v6b: + T5 s_setprio around QK^T and PV MFMA clusters (m191: attn
// +4-7% in exactly this independent-blocks regime).
#define KS_LD 136   // 64x128 K tile, padded (16B-aligned rows, 2-way bank aliasing)
#define VS_LD 72    // 128x64 V^T tile, padded
#define PS_LD 72    // 16x64 P tile per wave, padded
__global__ __launch_bounds__(256, 3)
void attn_fused(const unsigned short* __restrict__ Qb,
                const unsigned short* __restrict__ Kb,
                const unsigned short* __restrict__ Vt,
                unsigned short* __restrict__ Ob) {
  __shared__ __align__(16) unsigned short Ks[64 * KS_LD];
  __shared__ __align__(16) unsigned short Vts[128 * VS_LD];
  __shared__ __align__(16) unsigned short Ps[4 * 16 * PS_LD];

  const int tid = threadIdx.x, lane = tid & 63, w = tid >> 6;
  const int bh = blockIdx.x;                    // fast dim: spreads heads across XCDs
  const int qt = (gridDim.y - 1) - blockIdx.y;  // descending: longest blocks first (LPT)
  const int q0 = qt * 64;
  const int b = bh >> 4, h = bh & 15;
  const int rowq = lane & 15;
  const int koff = (lane >> 4) * 8;
  const int lr0 = (lane >> 4) * 4;
  const size_t qkbase = (size_t)bh * (S_ * HD_);
  const size_t vbase  = (size_t)bh * (HD_ * S_);

  bf16x8 qf0, qf1, qf2, qf3;
  {
    const unsigned short* qrow = Qb + qkbase + (size_t)(q0 + w * 16 + rowq) * HD_;
    qf0 = *(const bf16x8*)(qrow + 0 * 32 + koff);
    qf1 = *(const bf16x8*)(qrow + 1 * 32 + koff);
    qf2 = *(const bf16x8*)(qrow + 2 * 32 + koff);
    qf3 = *(const bf16x8*)(qrow + 3 * 32 + koff);
  }

  const int krow = tid >> 4, kcol = (tid & 15) * 8;  // K: 16 rows/pass
  const int vrow = tid >> 3, vcol = (tid & 7) * 8;   // V^T: 32 rows/pass
  const unsigned short* kptr = Kb + qkbase + (size_t)krow * HD_ + kcol;
  const unsigned short* vptr = Vt + vbase + (size_t)vrow * S_ + vcol;

  f32x4 oacc[8];
  for (int i = 0; i < 8; ++i)
    for (int r = 0; r < 4; ++r) oacc[i][r] = 0.f;
  float m_r[4] = {-3e38f, -3e38f, -3e38f, -3e38f};
  float l_r[4] = {0.f, 0.f, 0.f, 0.f};

  const int nkt = qt + 1;

  float4 k0, k1, k2, k3, v0, v1, v2, v3;
  k0 = *(const float4*)(kptr + 0 * 16 * HD_);
  k1 = *(const float4*)(kptr + 1 * 16 * HD_);
  k2 = *(const float4*)(kptr + 2 * 16 * HD_);
  k3 = *(const float4*)(kptr + 3 * 16 * HD_);
  v0 = *(const float4*)(vptr + 0 * 32 * S_);
  v1 = *(const float4*)(vptr + 1 * 32 * S_);
  v2 = *(const float4*)(vptr + 2 * 32 * S_);
  v3 = *(const float4*)(vptr + 3 * 32 * S_);

  for (int kt = 0; kt < nkt; ++kt) {
    __syncthreads();  // previous tile's readers done
    *(float4*)&Ks[(krow + 0 * 16) * KS_LD + kcol] = k0;
    *(float4*)&Ks[(krow + 1 * 16) * KS_LD + kcol] = k1;
    *(float4*)&Ks[(krow + 2 * 16) * KS_LD + kcol] = k2;
    *(float4*)&Ks[(krow + 3 * 16) * KS_LD + kcol] = k3;
    *(float4*)&Vts[(vrow + 0 * 32) * VS_LD + vcol] = v0;
    *(float4*)&Vts[(vrow + 1 * 32) * VS_LD + vcol] = v1;
    *(float4*)&Vts[(vrow + 2 * 32) * VS_LD + vcol] = v2;
    *(float4*)&Vts[(vrow + 3 * 32) * VS_LD + vcol] = v3;
    if (kt + 1 < nkt) {
      const unsigned short* kp = kptr + (size_t)(kt + 1) * 64 * HD_;
      k0 = *(const float4*)(kp + 0 * 16 * HD_);
      k1 = *(const float4*)(kp + 1 * 16 * HD_);
      k2 = *(const float4*)(kp + 2 * 16 * HD_);
      k3 = *(const float4*)(kp + 3 * 16 * HD_);
    }
    __syncthreads();

    f32x4 sacc[4];
    for (int n = 0; n < 4; ++n)
      for (int r = 0; r < 4; ++r) sacc[n][r] = 0.f;
    __builtin_amdgcn_s_setprio(1);
#pragma unroll
    for (int n = 0; n < 4; ++n) {
      const unsigned short* krow_p = &Ks[(n * 16 + rowq) * KS_LD + koff];
      sacc[n] = __builtin_amdgcn_mfma_f32_16x16x32_bf16(qf0, *(const bf16x8*)(krow_p + 0 * 32), sacc[n], 0, 0, 0);
      sacc[n] = __builtin_amdgcn_mfma_f32_16x16x32_bf16(qf1, *(const bf16x8*)(krow_p + 1 * 32), sacc[n], 0, 0, 0);
      sacc[n] = __builtin_amdgcn_mfma_f32_16x16x32_bf16(qf2, *(const bf16x8*)(krow_p + 2 * 32), sacc[n], 0, 0, 0);
      sacc[n] = __builtin_amdgcn_mfma_f32_16x16x32_bf16(qf3, *(const bf16x8*)(krow_p + 3 * 32), sacc[n], 0, 0, 0);
    }
    __builtin_amdgcn_s_setprio(0);

    float tmax[4] = {-3e38f, -3e38f, -3e38f, -3e38f};
    if (kt == qt) {
      for (int n = 0; n < 4; ++n) {
        int col = n * 16 + rowq;
        for (int r = 0; r < 4; ++r) {
          int row = w * 16 + lr0 + r;
          float x = (col <= row) ? sacc[n][r] : -1e30f;
          sacc[n][r] = x;
          tmax[r] = fmaxf(tmax[r], x);
        }
      }
    } else {
      for (int n = 0; n < 4; ++n)
        for (int r = 0; r < 4; ++r)
          tmax[r] = fmaxf(tmax[r], sacc[n][r]);
    }
    for (int off = 1; off < 16; off <<= 1)
      for (int r = 0; r < 4; ++r) tmax[r] = fmaxf(tmax[r], __shfl_xor(tmax[r], off));
    float alpha[4];
    for (int r = 0; r < 4; ++r) {
      float mn = fmaxf(m_r[r], tmax[r]);
      alpha[r] = __builtin_amdgcn_exp2f(m_r[r] - mn);
      m_r[r] = mn;
    }
    float rs[4] = {0.f, 0.f, 0.f, 0.f};
    for (int n = 0; n < 4; ++n)
      for (int r = 0; r < 4; ++r) {
        float p = __builtin_amdgcn_exp2f(sacc[n][r] - m_r[r]);
        sacc[n][r] = p;
        rs[r] += p;
      }
    for (int off = 1; off < 16; off <<= 1)
      for (int r = 0; r < 4; ++r) rs[r] += __shfl_xor(rs[r], off);
    for (int r = 0; r < 4; ++r) l_r[r] = l_r[r] * alpha[r] + rs[r];
    for (int nd = 0; nd < 8; ++nd)
      for (int r = 0; r < 4; ++r) oacc[nd][r] *= alpha[r];

    if (kt + 1 < nkt) {
      const unsigned short* vp = vptr + (size_t)(kt + 1) * 64;
      v0 = *(const float4*)(vp + 0 * 32 * S_);
      v1 = *(const float4*)(vp + 1 * 32 * S_);
      v2 = *(const float4*)(vp + 2 * 32 * S_);
      v3 = *(const float4*)(vp + 3 * 32 * S_);
    }

    unsigned short* pw = &Ps[w * 16 * PS_LD];
    for (int n = 0; n < 4; ++n)
      for (int r = 0; r < 4; ++r)
        pw[(lr0 + r) * PS_LD + n * 16 + rowq] = f2bf(sacc[n][r]);

    __builtin_amdgcn_s_setprio(1);
#pragma unroll
    for (int t2 = 0; t2 < 2; ++t2) {
      bf16x8 pa = *(const bf16x8*)&pw[rowq * PS_LD + t2 * 32 + koff];
      for (int nd = 0; nd < 8; ++nd) {
        bf16x8 vb = *(const bf16x8*)&Vts[(nd * 16 + rowq) * VS_LD + t2 * 32 + koff];
        oacc[nd] = __builtin_amdgcn_mfma_f32_16x16x32_bf16(pa, vb, oacc[nd], 0, 0, 0);
      }
    }
    __builtin_amdgcn_s_setprio(0);
  }

  float linv[4];
  for (int r = 0; r < 4; ++r) linv[r] = __builtin_amdgcn_rcpf(l_r[r]);
  for (int nd = 0; nd < 8; ++nd) {
    int col = h * HD_ + nd * 16 + rowq;
    for (int r = 0; r < 4; ++r) {
      int row = q0 + w * 16 + lr0 + r;
      Ob[(size_t)(b * S_ + row) * HID_ + col] = f2bf(oacc[nd][r] * linv[r]);
    }
  }
}

// ---------------- launcher ----------------
extern "C" void kernel_launch(void* const* d_in, const int* in_sizes, int n_in,
                              void* d_out, int out_size, void* d_ws, size_t ws_size,
                              hipStream_t stream) {
  (void)in_sizes; (void)n_in; (void)out_size; (void)ws_size;
  const float* hidden = (const float*)d_in[0];
  // d_in[1] = attention_mask (causal; reproduced analytically)
  const int* pos = (const int*)d_in[2];
  const float* Wq = (const float*)d_in[3];
  const float* Wk = (const float*)d_in[4];
  const float* Wv = (const float*)d_in[5];
  const float* Wo = (const float*)d_in[6];
  float* out = (float*)d_out;

  char* ws = (char*)d_ws;
  unsigned short* Xb   = (unsigned short*)(ws);               // 16 MB  (B,S,HID) bf16
  unsigned short* Wqb  = (unsigned short*)(ws + 16777216);    // 8 MB  Wq -- Wqb/Wkb/Wvb contiguous:
  unsigned short* Wkb  = (unsigned short*)(ws + 25165824);    // 8 MB  Wk -- one (6144,2048) QKV weight
  unsigned short* Wvb  = (unsigned short*)(ws + 33554432);    // 8 MB  Wv
  unsigned short* Wob  = (unsigned short*)(ws + 41943040);    // 8 MB
  unsigned short* Qb   = (unsigned short*)(ws + 50331648);    // 16 MB (B,NH,S,HD)
  unsigned short* Kb   = (unsigned short*)(ws + 67108864);    // 16 MB
  unsigned short* Vtmp = (unsigned short*)(ws + 83886080);    // 16 MB (B,S,HID)
  unsigned short* Vtb  = (unsigned short*)(ws + 100663296);   // 16 MB (B,NH,HD,S)
  unsigned short* Ob   = Xb;          // Xb dead after QKV GEMM
  float2* tbl          = (float2*)ws; // RoPE table also lives in dead Xb region (1 MB)

  cast_all<<<2048, 256, 0, stream>>>(hidden, Wq, Wk, Wv, Wo, Xb, Wqb, Wkb, Wvb, Wob);

  // fused QKV: C (4096 x 6144) = X (4096x2048) * Wqkv^T, 256x192 tiles
  dim3 gq(3 * HID_ / 192, (B_ * S_) / 256);  // (32, 16) = 512 blocks = exactly 2 rounds
  gemm_qkv<<<gq, 512, 0, stream>>>(Xb, Wqb, Qb, Kb, Vtmp);

  rope_table<<<(MAXTOK_ * 64) / 256, 256, 0, stream>>>(tbl);
  rope_apply<<<(B_ * NH_ * S_ * 8) / 256, 256, 0, stream>>>(Qb, Kb, pos, tbl);

  dim3 tg(S_ / 64, HD_ / 64, B_ * NH_);  // (32, 2, 32)
  transpose_v<<<tg, 256, 0, stream>>>(Vtmp, Vtb);

  dim3 ag(B_ * NH_, S_ / 64);  // bh fast, qt slow (descending inside kernel)
  attn_fused<<<ag, 256, 0, stream>>>(Qb, Kb, Vtb, Ob);

  dim3 go(HID_ / 128, (B_ * S_) / 256);  // (16, 16) = 256 blocks = exactly 1 round
  gemm_out<<<go, 512, 0, stream>>>(Ob, Wob, out);
}

// Round 9
// 393.543 us; speedup vs baseline: 1.0519x; 1.0092x over previous
//
#include <hip/hip_runtime.h>

#define B_   2
#define S_   2048
#define HID_ 2048
#define NH_  16
#define HD_  128
#define MAXTOK_ 2048

typedef float  f32x4  __attribute__((ext_vector_type(4)));
typedef __bf16 bf16x8 __attribute__((ext_vector_type(8)));
typedef unsigned short u16x8 __attribute__((ext_vector_type(8)));

__device__ __forceinline__ unsigned short f2bf(float f) {
  union { float fv; unsigned u; } v; v.fv = f;
  unsigned r = v.u + 0x7FFFu + ((v.u >> 16) & 1u);  // RNE
  return (unsigned short)(r >> 16);
}
__device__ __forceinline__ float bf2f(unsigned short h) {
  union { unsigned u; float fv; } v; v.u = ((unsigned)h) << 16;
  return v.fv;
}

// async global->LDS, 16B per lane (LDS dst must be linear/contiguous)
__device__ __forceinline__ void gload16(const void* g, void* lds) {
  __builtin_amdgcn_global_load_lds(
      (const __attribute__((address_space(1))) void*)g,
      (__attribute__((address_space(3))) void*)lds, 16, 0, 0);
}

// ---------------- fused cast fp32 -> bf16 for hidden + 4 weights ----------------
#define H4_ (B_ * S_ * HID_ / 4)
#define W4_ (HID_ * HID_ / 4)
__global__ void cast_all(const float* __restrict__ h,  const float* __restrict__ wq,
                         const float* __restrict__ wk, const float* __restrict__ wv,
                         const float* __restrict__ wo,
                         unsigned short* __restrict__ xb,  unsigned short* __restrict__ wqb,
                         unsigned short* __restrict__ wkb, unsigned short* __restrict__ wvb,
                         unsigned short* __restrict__ wob) {
  const int total = H4_ + 4 * W4_;
  int i = blockIdx.x * blockDim.x + threadIdx.x;
  int stride = gridDim.x * blockDim.x;
  for (; i < total; i += stride) {
    const float* src; unsigned short* dst; int j;
    if (i < H4_) { src = h; dst = xb; j = i; }
    else {
      int k = i - H4_, wsel = k >> 20;  // W4_ = 2^20
      j = k & (W4_ - 1);
      src = (wsel == 0) ? wq : (wsel == 1) ? wk : (wsel == 2) ? wv : wo;
      dst = (wsel == 0) ? wqb : (wsel == 1) ? wkb : (wsel == 2) ? wvb : wob;
    }
    float4 v = ((const float4*)src)[j];
    ushort4 o;
    o.x = f2bf(v.x); o.y = f2bf(v.y); o.z = f2bf(v.z); o.w = f2bf(v.w);
    ((ushort4*)dst)[j] = o;
  }
}

// ---------------- fused QKV projection: 256x192 tile, BK=64, 4-phase/K-tile ----------------
// Round-3 verified structure (107 us, MfmaUtil 40%, conflicts 0). UNCHANGED.
#define QKV_STG(gp, lp, rb) gload16((gp) + (size_t)(rb) * 2048, (lp) + (rb) * 64)

#define QKV_LOADA(Q) do { \
  _Pragma("unroll") \
  for (int mi_ = 0; mi_ < 2; ++mi_) { \
    const char* rp_ = (const char*)Acur + (size_t)((wm + (Q) * 32 + mi_ * 16 + rowq) * 128); \
    af[mi_][0] = *(const bf16x8*)(rp_ + cb0); \
    af[mi_][1] = *(const bf16x8*)(rp_ + cb1); \
  } } while (0)

#define QKV_LOADB() do { \
  _Pragma("unroll") \
  for (int ni_ = 0; ni_ < 3; ++ni_) { \
    const char* rp_ = (const char*)Bcur + (size_t)((wn + ni_ * 16 + rowq) * 128); \
    bfr[ni_][0] = *(const bf16x8*)(rp_ + cb0); \
    bfr[ni_][1] = *(const bf16x8*)(rp_ + cb1); \
  } } while (0)

#define QKV_MFMA(Q) do { \
  _Pragma("unroll") \
  for (int mi_ = 0; mi_ < 2; ++mi_) { \
    _Pragma("unroll") \
    for (int ni_ = 0; ni_ < 3; ++ni_) { \
      f32x4 c_ = acc[(Q) * 2 + mi_][ni_]; \
      c_ = __builtin_amdgcn_mfma_f32_16x16x32_bf16(af[mi_][0], bfr[ni_][0], c_, 0, 0, 0); \
      c_ = __builtin_amdgcn_mfma_f32_16x16x32_bf16(af[mi_][1], bfr[ni_][1], c_, 0, 0, 0); \
      acc[(Q) * 2 + mi_][ni_] = c_; \
    } } } while (0)

#define QKV_BAR    asm volatile("s_barrier" ::: "memory")
#define QKV_VMC4   asm volatile("s_waitcnt vmcnt(4)" ::: "memory")
#define QKV_VMC2   asm volatile("s_waitcnt vmcnt(2)" ::: "memory")
#define QKV_VMC0   asm volatile("s_waitcnt vmcnt(0)" ::: "memory")

__global__ __launch_bounds__(512, 2)
void gemm_qkv(const unsigned short* __restrict__ A,
              const unsigned short* __restrict__ Bw,
              unsigned short* __restrict__ Qb,
              unsigned short* __restrict__ Kb,
              unsigned short* __restrict__ Vtmp) {
  const int K = HID_;       // 2048
  const int NT = K / 64;    // 32 K-tiles
  __shared__ __align__(16) unsigned short As[2][256 * 64];
  __shared__ __align__(16) unsigned short Bs[2][192 * 64];

  const int tid = threadIdx.x, lane = tid & 63, w = tid >> 6;
  const int n0 = blockIdx.x * 192, m0 = blockIdx.y * 256;
  const int wm = (w >> 2) * 128, wn = (w & 3) * 48;
  const int rowq = lane & 15, klane = lane >> 4;
  const int sw  = (rowq & 7) << 4;
  const int cb0 = (klane * 16) ^ sw;          // ks=0 (slots 0..3)
  const int cb1 = ((klane + 4) * 16) ^ sw;    // ks=1 (slots 4..7)
  const int srow = tid >> 3;                  // 0..63
  const int dc8  = (tid & 7) * 8;             // linear lds col (elements)
  const int scol = (((tid & 7) * 16) ^ ((srow & 7) << 4)) >> 1;  // global col (elems)

  const unsigned short* Ag = A  + (size_t)(m0 + srow) * K + scol;
  const unsigned short* Bg = Bw + (size_t)(n0 + srow) * K + scol;

  f32x4 acc[8][3];
#pragma unroll
  for (int i = 0; i < 8; ++i)
#pragma unroll
    for (int j = 0; j < 3; ++j)
#pragma unroll
      for (int r = 0; r < 4; ++r) acc[i][j][r] = 0.f;

  bf16x8 af[2][2], bfr[3][2];

  {
    unsigned short* Al = (unsigned short*)&As[0][0] + srow * 64 + dc8;
    unsigned short* Bl = (unsigned short*)&Bs[0][0] + srow * 64 + dc8;
    QKV_STG(Bg, Bl, 0); QKV_STG(Bg, Bl, 64); QKV_STG(Bg, Bl, 128);
    QKV_STG(Ag, Al, 0); QKV_STG(Ag, Al, 128);
    QKV_STG(Ag, Al, 64); QKV_STG(Ag, Al, 192);
  }
  QKV_VMC2;   // oldest 5 (B0,B1,B2,A0,A2) landed
  QKV_BAR;

  const unsigned short* Acur = &As[0][0];
  const unsigned short* Bcur = &Bs[0][0];
  unsigned short* Anx = (unsigned short*)&As[1][0];
  unsigned short* Bnx = (unsigned short*)&Bs[1][0];

  for (int t = 0; t < NT - 1; ++t) {
    const int kn = (t + 1) * 64;
    const unsigned short* Agk = Ag + kn;
    const unsigned short* Bgk = Bg + kn;
    unsigned short* Al = Anx + srow * 64 + dc8;
    unsigned short* Bl = Bnx + srow * 64 + dc8;

    QKV_LOADA(0); QKV_LOADB();
    QKV_STG(Bgk, Bl, 0); QKV_STG(Bgk, Bl, 64);
    QKV_BAR;
    __builtin_amdgcn_s_setprio(1); QKV_MFMA(0); __builtin_amdgcn_s_setprio(0);
    QKV_BAR;
    QKV_LOADA(1);
    QKV_STG(Bgk, Bl, 128); QKV_STG(Agk, Al, 0);
    QKV_BAR;
    __builtin_amdgcn_s_setprio(1); QKV_MFMA(1); __builtin_amdgcn_s_setprio(0);
    QKV_VMC4;
    QKV_BAR;
    QKV_LOADA(2);
    QKV_STG(Agk, Al, 128); QKV_STG(Agk, Al, 64);
    QKV_BAR;
    __builtin_amdgcn_s_setprio(1); QKV_MFMA(2); __builtin_amdgcn_s_setprio(0);
    QKV_BAR;
    QKV_LOADA(3);
    QKV_STG(Agk, Al, 192);
    QKV_BAR;
    __builtin_amdgcn_s_setprio(1); QKV_MFMA(3); __builtin_amdgcn_s_setprio(0);
    QKV_VMC2;
    QKV_BAR;

    { const unsigned short* tp = Acur; Acur = Anx; Anx = (unsigned short*)tp; }
    { const unsigned short* tp = Bcur; Bcur = Bnx; Bnx = (unsigned short*)tp; }
  }

  QKV_LOADA(0); QKV_LOADB();
  QKV_BAR;
  __builtin_amdgcn_s_setprio(1); QKV_MFMA(0); __builtin_amdgcn_s_setprio(0);
  QKV_BAR;
  QKV_LOADA(1);
  QKV_BAR;
  __builtin_amdgcn_s_setprio(1); QKV_MFMA(1); __builtin_amdgcn_s_setprio(0);
  QKV_VMC0;
  QKV_BAR;
  QKV_LOADA(2);
  QKV_BAR;
  __builtin_amdgcn_s_setprio(1); QKV_MFMA(2); __builtin_amdgcn_s_setprio(0);
  QKV_BAR;
  QKV_LOADA(3);
  __builtin_amdgcn_s_setprio(1); QKV_MFMA(3); __builtin_amdgcn_s_setprio(0);

  const int lr0 = klane * 4;
#pragma unroll
  for (int mi = 0; mi < 8; ++mi)
#pragma unroll
    for (int ni = 0; ni < 3; ++ni)
#pragma unroll
      for (int r = 0; r < 4; ++r) {
        int r_ = m0 + wm + mi * 16 + lr0 + r;
        int c_ = n0 + wn + ni * 16 + rowq;
        float v = acc[mi][ni][r];
        int b = r_ >> 11, s = r_ & 2047;
        int proj = c_ >> 11, cin = c_ & 2047;
        if (proj == 2) {
          Vtmp[(size_t)(b * S_ + s) * HID_ + cin] = f2bf(v);
        } else {
          int hh = cin >> 7, d = cin & 127;
          unsigned short* dst = (proj == 0) ? Qb : Kb;
          dst[(((size_t)(b * NH_ + hh) * S_ + s) * HD_) + d] = f2bf(v);
        }
      }
}

// ---------------- output projection: 256x128 tile, BK=64, 4-phase/K-tile ----------------
#define OUT_LOADA(Q) do { \
  _Pragma("unroll") \
  for (int mi_ = 0; mi_ < 2; ++mi_) { \
    const char* rp_ = (const char*)Acur + (size_t)((wm + (Q) * 32 + mi_ * 16 + rowq) * 128); \
    af[mi_][0] = *(const bf16x8*)(rp_ + cb0); \
    af[mi_][1] = *(const bf16x8*)(rp_ + cb1); \
  } } while (0)

#define OUT_LOADB() do { \
  _Pragma("unroll") \
  for (int ni_ = 0; ni_ < 2; ++ni_) { \
    const char* rp_ = (const char*)Bcur + (size_t)((wn + ni_ * 16 + rowq) * 128); \
    bfr[ni_][0] = *(const bf16x8*)(rp_ + cb0); \
    bfr[ni_][1] = *(const bf16x8*)(rp_ + cb1); \
  } } while (0)

#define OUT_MFMA(Q) do { \
  _Pragma("unroll") \
  for (int mi_ = 0; mi_ < 2; ++mi_) { \
    _Pragma("unroll") \
    for (int ni_ = 0; ni_ < 2; ++ni_) { \
      f32x4 c_ = acc[(Q) * 2 + mi_][ni_]; \
      c_ = __builtin_amdgcn_mfma_f32_16x16x32_bf16(af[mi_][0], bfr[ni_][0], c_, 0, 0, 0); \
      c_ = __builtin_amdgcn_mfma_f32_16x16x32_bf16(af[mi_][1], bfr[ni_][1], c_, 0, 0, 0); \
      acc[(Q) * 2 + mi_][ni_] = c_; \
    } } } while (0)

__global__ __launch_bounds__(512, 2)
void gemm_out(const unsigned short* __restrict__ A,
              const unsigned short* __restrict__ Bw,
              float* __restrict__ Cout) {
  const int K = HID_, N = HID_;
  const int NT = K / 64;    // 32
  __shared__ __align__(16) unsigned short As[2][256 * 64];
  __shared__ __align__(16) unsigned short Bs[2][128 * 64];

  const int tid = threadIdx.x, lane = tid & 63, w = tid >> 6;
  const int n0 = blockIdx.x * 128, m0 = blockIdx.y * 256;
  const int wm = (w >> 2) * 128, wn = (w & 3) * 32;
  const int rowq = lane & 15, klane = lane >> 4;
  const int sw  = (rowq & 7) << 4;
  const int cb0 = (klane * 16) ^ sw;
  const int cb1 = ((klane + 4) * 16) ^ sw;
  const int srow = tid >> 3;
  const int dc8  = (tid & 7) * 8;
  const int scol = (((tid & 7) * 16) ^ ((srow & 7) << 4)) >> 1;

  const unsigned short* Ag = A  + (size_t)(m0 + srow) * K + scol;
  const unsigned short* Bg = Bw + (size_t)(n0 + srow) * K + scol;

  f32x4 acc[8][2];
#pragma unroll
  for (int i = 0; i < 8; ++i)
#pragma unroll
    for (int j = 0; j < 2; ++j)
#pragma unroll
      for (int r = 0; r < 4; ++r) acc[i][j][r] = 0.f;

  bf16x8 af[2][2], bfr[2][2];

  {
    unsigned short* Al = (unsigned short*)&As[0][0] + srow * 64 + dc8;
    unsigned short* Bl = (unsigned short*)&Bs[0][0] + srow * 64 + dc8;
    QKV_STG(Bg, Bl, 0); QKV_STG(Bg, Bl, 64);
    QKV_STG(Ag, Al, 0); QKV_STG(Ag, Al, 128);
    QKV_STG(Ag, Al, 64); QKV_STG(Ag, Al, 192);
  }
  QKV_VMC2;   // oldest 4 (B0,B1,A0,A2) landed
  QKV_BAR;

  const unsigned short* Acur = &As[0][0];
  const unsigned short* Bcur = &Bs[0][0];
  unsigned short* Anx = (unsigned short*)&As[1][0];
  unsigned short* Bnx = (unsigned short*)&Bs[1][0];

  for (int t = 0; t < NT - 1; ++t) {
    const int kn = (t + 1) * 64;
    const unsigned short* Agk = Ag + kn;
    const unsigned short* Bgk = Bg + kn;
    unsigned short* Al = Anx + srow * 64 + dc8;
    unsigned short* Bl = Bnx + srow * 64 + dc8;

    OUT_LOADA(0); OUT_LOADB();
    QKV_STG(Bgk, Bl, 0); QKV_STG(Bgk, Bl, 64);
    QKV_BAR;
    __builtin_amdgcn_s_setprio(1); OUT_MFMA(0); __builtin_amdgcn_s_setprio(0);
    QKV_BAR;
    OUT_LOADA(1);
    QKV_STG(Agk, Al, 0); QKV_STG(Agk, Al, 128);
    QKV_BAR;
    __builtin_amdgcn_s_setprio(1); OUT_MFMA(1); __builtin_amdgcn_s_setprio(0);
    QKV_VMC4;
    QKV_BAR;
    OUT_LOADA(2);
    QKV_STG(Agk, Al, 64);
    QKV_BAR;
    __builtin_amdgcn_s_setprio(1); OUT_MFMA(2); __builtin_amdgcn_s_setprio(0);
    QKV_BAR;
    OUT_LOADA(3);
    QKV_STG(Agk, Al, 192);
    QKV_BAR;
    __builtin_amdgcn_s_setprio(1); OUT_MFMA(3); __builtin_amdgcn_s_setprio(0);
    QKV_VMC2;
    QKV_BAR;

    { const unsigned short* tp = Acur; Acur = Anx; Anx = (unsigned short*)tp; }
    { const unsigned short* tp = Bcur; Bcur = Bnx; Bnx = (unsigned short*)tp; }
  }

  OUT_LOADA(0); OUT_LOADB();
  QKV_BAR;
  __builtin_amdgcn_s_setprio(1); OUT_MFMA(0); __builtin_amdgcn_s_setprio(0);
  QKV_BAR;
  OUT_LOADA(1);
  QKV_BAR;
  __builtin_amdgcn_s_setprio(1); OUT_MFMA(1); __builtin_amdgcn_s_setprio(0);
  QKV_VMC0;
  QKV_BAR;
  OUT_LOADA(2);
  QKV_BAR;
  __builtin_amdgcn_s_setprio(1); OUT_MFMA(2); __builtin_amdgcn_s_setprio(0);
  QKV_BAR;
  OUT_LOADA(3);
  __builtin_amdgcn_s_setprio(1); OUT_MFMA(3); __builtin_amdgcn_s_setprio(0);

  const int lr0 = klane * 4;
#pragma unroll
  for (int mi = 0; mi < 8; ++mi)
#pragma unroll
    for (int ni = 0; ni < 2; ++ni)
#pragma unroll
      for (int r = 0; r < 4; ++r) {
        int r_ = m0 + wm + mi * 16 + lr0 + r;
        int c_ = n0 + wn + ni * 16 + rowq;
        Cout[(size_t)r_ * N + c_] = acc[mi][ni][r];
      }
}

// ---------------- fused RoPE (inline trig) + V transpose ----------------
// rope_table eliminated: cos/sin computed inline (8 expf + 8 sincosf per
// thread ~ 2.7 us total VALU, identical numerics to the table version).
// rope_apply and transpose_v fused into one launch (disjoint data, no
// ordering dependency); block-uniform branch on blockIdx.x.
#define QSCALE_ 0.12751744f
#define ROPE_BLOCKS_ (B_ * NH_ * S_ * 8 / 256)      // 8192
#define TRANS_BLOCKS_ ((S_ / 64) * (HD_ / 64) * B_ * NH_)  // 2048
__global__ __launch_bounds__(256)
void rope_transpose(unsigned short* __restrict__ Qb, unsigned short* __restrict__ Kb,
                    const int* __restrict__ pos_ids,
                    const unsigned short* __restrict__ Vin,
                    unsigned short* __restrict__ Vt) {
  __shared__ __align__(16) unsigned short t[64 * 72];
  const int bid = blockIdx.x;
  if (bid < ROPE_BLOCKS_) {
    int i = bid * 256 + threadIdx.x;  // bhs*8 + t8
    int t8 = i & 7, bhs = i >> 3;
    int s = bhs & (S_ - 1);
    int b = bhs >> 15;  // NH_*S_ = 32768
    int d0 = t8 * 8;
    int p = pos_ids[b * S_ + s];
    float cs[8], sn[8];
#pragma unroll
    for (int j = 0; j < 8; ++j) {
      float f = __expf(-(float)(d0 + j) * (9.210340371976184f / 64.f));  // 10000^(-d/64)
      __sincosf((float)p * f, &sn[j], &cs[j]);
    }
    size_t base = (size_t)bhs * HD_ + d0;
    {
      u16x8 x1 = *(const u16x8*)(Qb + base);
      u16x8 x2 = *(const u16x8*)(Qb + base + 64);
      u16x8 o1, o2;
#pragma unroll
      for (int j = 0; j < 8; ++j) {
        float a = bf2f(x1[j]), bb = bf2f(x2[j]);
        o1[j] = f2bf((a * cs[j] - bb * sn[j]) * QSCALE_);
        o2[j] = f2bf((bb * cs[j] + a * sn[j]) * QSCALE_);
      }
      *(u16x8*)(Qb + base) = o1;
      *(u16x8*)(Qb + base + 64) = o2;
    }
    {
      u16x8 x1 = *(const u16x8*)(Kb + base);
      u16x8 x2 = *(const u16x8*)(Kb + base + 64);
      u16x8 o1, o2;
#pragma unroll
      for (int j = 0; j < 8; ++j) {
        float a = bf2f(x1[j]), bb = bf2f(x2[j]);
        o1[j] = f2bf(a * cs[j] - bb * sn[j]);
        o2[j] = f2bf(bb * cs[j] + a * sn[j]);
      }
      *(u16x8*)(Kb + base) = o1;
      *(u16x8*)(Kb + base + 64) = o2;
    }
  } else {
    int idx = bid - ROPE_BLOCKS_;
    const int s0 = (idx & 31) * 64, d0v = ((idx >> 5) & 1) * 64, bh = idx >> 6;
    const int b = bh >> 4, h = bh & 15;
    const int tid = threadIdx.x;
#pragma unroll
    for (int it = 0; it < 2; ++it) {
      int chunk = it * 256 + tid;          // 512 chunks of 8 elems
      int sl = chunk >> 3, dc = (chunk & 7) * 8;
      u16x8 v = *(const u16x8*)&Vin[(size_t)(b * S_ + s0 + sl) * HID_ + h * HD_ + d0v + dc];
      *(u16x8*)&t[sl * 72 + dc] = v;
    }
    __syncthreads();
#pragma unroll
    for (int it = 0; it < 2; ++it) {
      int lin = it * 256 + tid;
      int dl = lin & 63, sq = (lin >> 6) * 8;  // lanes span dl -> banks spread
      u16x8 v;
#pragma unroll
      for (int j = 0; j < 8; ++j) v[j] = t[(sq + j) * 72 + dl];
      *(u16x8*)&Vt[((size_t)bh * HD_ + d0v + dl) * S_ + s0 + sq] = v;
    }
  }
}

// ---------------- fused causal flash attention (v6c) ----------------
// v6b (best-measured: QBLK 64, 256 thr, 3 blocks/CU, setprio on MFMA clusters)
// + T13 defer-max: skip the alpha/O-rescale pass when no row's tile-max
// exceeds the running max by >8 (exp2 domain -> P <= 256, safe in bf16/fp32).
// Measured +5% on attn (m214/m239, data-independent). Wave-uniform branch.
#define KS_LD 136   // 64x128 K tile, padded (16B-aligned rows, 2-way bank aliasing)
#define VS_LD 72    // 128x64 V^T tile, padded
#define PS_LD 72    // 16x64 P tile per wave, padded
__global__ __launch_bounds__(256, 3)
void attn_fused(const unsigned short* __restrict__ Qb,
                const unsigned short* __restrict__ Kb,
                const unsigned short* __restrict__ Vt,
                unsigned short* __restrict__ Ob) {
  __shared__ __align__(16) unsigned short Ks[64 * KS_LD];
  __shared__ __align__(16) unsigned short Vts[128 * VS_LD];
  __shared__ __align__(16) unsigned short Ps[4 * 16 * PS_LD];

  const int tid = threadIdx.x, lane = tid & 63, w = tid >> 6;
  const int bh = blockIdx.x;                    // fast dim: spreads heads across XCDs
  const int qt = (gridDim.y - 1) - blockIdx.y;  // descending: longest blocks first (LPT)
  const int q0 = qt * 64;
  const int b = bh >> 4, h = bh & 15;
  const int rowq = lane & 15;
  const int koff = (lane >> 4) * 8;
  const int lr0 = (lane >> 4) * 4;
  const size_t qkbase = (size_t)bh * (S_ * HD_);
  const size_t vbase  = (size_t)bh * (HD_ * S_);

  bf16x8 qf0, qf1, qf2, qf3;
  {
    const unsigned short* qrow = Qb + qkbase + (size_t)(q0 + w * 16 + rowq) * HD_;
    qf0 = *(const bf16x8*)(qrow + 0 * 32 + koff);
    qf1 = *(const bf16x8*)(qrow + 1 * 32 + koff);
    qf2 = *(const bf16x8*)(qrow + 2 * 32 + koff);
    qf3 = *(const bf16x8*)(qrow + 3 * 32 + koff);
  }

  const int krow = tid >> 4, kcol = (tid & 15) * 8;  // K: 16 rows/pass
  const int vrow = tid >> 3, vcol = (tid & 7) * 8;   // V^T: 32 rows/pass
  const unsigned short* kptr = Kb + qkbase + (size_t)krow * HD_ + kcol;
  const unsigned short* vptr = Vt + vbase + (size_t)vrow * S_ + vcol;

  f32x4 oacc[8];
  for (int i = 0; i < 8; ++i)
    for (int r = 0; r < 4; ++r) oacc[i][r] = 0.f;
  float m_r[4] = {-3e38f, -3e38f, -3e38f, -3e38f};
  float l_r[4] = {0.f, 0.f, 0.f, 0.f};

  const int nkt = qt + 1;

  float4 k0, k1, k2, k3, v0, v1, v2, v3;
  k0 = *(const float4*)(kptr + 0 * 16 * HD_);
  k1 = *(const float4*)(kptr + 1 * 16 * HD_);
  k2 = *(const float4*)(kptr + 2 * 16 * HD_);
  k3 = *(const float4*)(kptr + 3 * 16 * HD_);
  v0 = *(const float4*)(vptr + 0 * 32 * S_);
  v1 = *(const float4*)(vptr + 1 * 32 * S_);
  v2 = *(const float4*)(vptr + 2 * 32 * S_);
  v3 = *(const float4*)(vptr + 3 * 32 * S_);

  for (int kt = 0; kt < nkt; ++kt) {
    __syncthreads();  // previous tile's readers done
    *(float4*)&Ks[(krow + 0 * 16) * KS_LD + kcol] = k0;
    *(float4*)&Ks[(krow + 1 * 16) * KS_LD + kcol] = k1;
    *(float4*)&Ks[(krow + 2 * 16) * KS_LD + kcol] = k2;
    *(float4*)&Ks[(krow + 3 * 16) * KS_LD + kcol] = k3;
    *(float4*)&Vts[(vrow + 0 * 32) * VS_LD + vcol] = v0;
    *(float4*)&Vts[(vrow + 1 * 32) * VS_LD + vcol] = v1;
    *(float4*)&Vts[(vrow + 2 * 32) * VS_LD + vcol] = v2;
    *(float4*)&Vts[(vrow + 3 * 32) * VS_LD + vcol] = v3;
    if (kt + 1 < nkt) {
      const unsigned short* kp = kptr + (size_t)(kt + 1) * 64 * HD_;
      k0 = *(const float4*)(kp + 0 * 16 * HD_);
      k1 = *(const float4*)(kp + 1 * 16 * HD_);
      k2 = *(const float4*)(kp + 2 * 16 * HD_);
      k3 = *(const float4*)(kp + 3 * 16 * HD_);
    }
    __syncthreads();

    f32x4 sacc[4];
    for (int n = 0; n < 4; ++n)
      for (int r = 0; r < 4; ++r) sacc[n][r] = 0.f;
    __builtin_amdgcn_s_setprio(1);
#pragma unroll
    for (int n = 0; n < 4; ++n) {
      const unsigned short* krow_p = &Ks[(n * 16 + rowq) * KS_LD + koff];
      sacc[n] = __builtin_amdgcn_mfma_f32_16x16x32_bf16(qf0, *(const bf16x8*)(krow_p + 0 * 32), sacc[n], 0, 0, 0);
      sacc[n] = __builtin_amdgcn_mfma_f32_16x16x32_bf16(qf1, *(const bf16x8*)(krow_p + 1 * 32), sacc[n], 0, 0, 0);
      sacc[n] = __builtin_amdgcn_mfma_f32_16x16x32_bf16(qf2, *(const bf16x8*)(krow_p + 2 * 32), sacc[n], 0, 0, 0);
      sacc[n] = __builtin_amdgcn_mfma_f32_16x16x32_bf16(qf3, *(const bf16x8*)(krow_p + 3 * 32), sacc[n], 0, 0, 0);
    }
    __builtin_amdgcn_s_setprio(0);

    float tmax[4] = {-3e38f, -3e38f, -3e38f, -3e38f};
    if (kt == qt) {
      for (int n = 0; n < 4; ++n) {
        int col = n * 16 + rowq;
        for (int r = 0; r < 4; ++r) {
          int row = w * 16 + lr0 + r;
          float x = (col <= row) ? sacc[n][r] : -1e30f;
          sacc[n][r] = x;
          tmax[r] = fmaxf(tmax[r], x);
        }
      }
    } else {
      for (int n = 0; n < 4; ++n)
        for (int r = 0; r < 4; ++r)
          tmax[r] = fmaxf(tmax[r], sacc[n][r]);
    }
    for (int off = 1; off < 16; off <<= 1)
      for (int r = 0; r < 4; ++r) tmax[r] = fmaxf(tmax[r], __shfl_xor(tmax[r], off));

    // T13 defer-max: rescale only if some row's max grew by >8 (exp2 units)
    float ex = -1.f;
    for (int r = 0; r < 4; ++r) ex = fmaxf(ex, tmax[r] - m_r[r]);
    if (__any(ex > 8.f)) {
      for (int r = 0; r < 4; ++r) {
        float mn = fmaxf(m_r[r], tmax[r]);
        float a = __builtin_amdgcn_exp2f(m_r[r] - mn);
        m_r[r] = mn;
        l_r[r] *= a;
        for (int nd = 0; nd < 8; ++nd) oacc[nd][r] *= a;
      }
    }
    float rs[4] = {0.f, 0.f, 0.f, 0.f};
    for (int n = 0; n < 4; ++n)
      for (int r = 0; r < 4; ++r) {
        float p = __builtin_amdgcn_exp2f(sacc[n][r] - m_r[r]);
        sacc[n][r] = p;
        rs[r] += p;
      }
    for (int off = 1; off < 16; off <<= 1)
      for (int r = 0; r < 4; ++r) rs[r] += __shfl_xor(rs[r], off);
    for (int r = 0; r < 4; ++r) l_r[r] += rs[r];

    if (kt + 1 < nkt) {
      const unsigned short* vp = vptr + (size_t)(kt + 1) * 64;
      v0 = *(const float4*)(vp + 0 * 32 * S_);
      v1 = *(const float4*)(vp + 1 * 32 * S_);
      v2 = *(const float4*)(vp + 2 * 32 * S_);
      v3 = *(const float4*)(vp + 3 * 32 * S_);
    }

    unsigned short* pw = &Ps[w * 16 * PS_LD];
    for (int n = 0; n < 4; ++n)
      for (int r = 0; r < 4; ++r)
        pw[(lr0 + r) * PS_LD + n * 16 + rowq] = f2bf(sacc[n][r]);

    __builtin_amdgcn_s_setprio(1);
#pragma unroll
    for (int t2 = 0; t2 < 2; ++t2) {
      bf16x8 pa = *(const bf16x8*)&pw[rowq * PS_LD + t2 * 32 + koff];
      for (int nd = 0; nd < 8; ++nd) {
        bf16x8 vb = *(const bf16x8*)&Vts[(nd * 16 + rowq) * VS_LD + t2 * 32 + koff];
        oacc[nd] = __builtin_amdgcn_mfma_f32_16x16x32_bf16(pa, vb, oacc[nd], 0, 0, 0);
      }
    }
    __builtin_amdgcn_s_setprio(0);
  }

  float linv[4];
  for (int r = 0; r < 4; ++r) linv[r] = __builtin_amdgcn_rcpf(l_r[r]);
  for (int nd = 0; nd < 8; ++nd) {
    int col = h * HD_ + nd * 16 + rowq;
    for (int r = 0; r < 4; ++r) {
      int row = q0 + w * 16 + lr0 + r;
      Ob[(size_t)(b * S_ + row) * HID_ + col] = f2bf(oacc[nd][r] * linv[r]);
    }
  }
}

// ---------------- launcher ----------------
extern "C" void kernel_launch(void* const* d_in, const int* in_sizes, int n_in,
                              void* d_out, int out_size, void* d_ws, size_t ws_size,
                              hipStream_t stream) {
  (void)in_sizes; (void)n_in; (void)out_size; (void)ws_size;
  const float* hidden = (const float*)d_in[0];
  // d_in[1] = attention_mask (causal; reproduced analytically)
  const int* pos = (const int*)d_in[2];
  const float* Wq = (const float*)d_in[3];
  const float* Wk = (const float*)d_in[4];
  const float* Wv = (const float*)d_in[5];
  const float* Wo = (const float*)d_in[6];
  float* out = (float*)d_out;

  char* ws = (char*)d_ws;
  unsigned short* Xb   = (unsigned short*)(ws);               // 16 MB  (B,S,HID) bf16
  unsigned short* Wqb  = (unsigned short*)(ws + 16777216);    // 8 MB  Wq -- Wqb/Wkb/Wvb contiguous:
  unsigned short* Wkb  = (unsigned short*)(ws + 25165824);    // 8 MB  Wk -- one (6144,2048) QKV weight
  unsigned short* Wvb  = (unsigned short*)(ws + 33554432);    // 8 MB  Wv
  unsigned short* Wob  = (unsigned short*)(ws + 41943040);    // 8 MB
  unsigned short* Qb   = (unsigned short*)(ws + 50331648);    // 16 MB (B,NH,S,HD)
  unsigned short* Kb   = (unsigned short*)(ws + 67108864);    // 16 MB
  unsigned short* Vtmp = (unsigned short*)(ws + 83886080);    // 16 MB (B,S,HID)
  unsigned short* Vtb  = (unsigned short*)(ws + 100663296);   // 16 MB (B,NH,HD,S)
  unsigned short* Ob   = Xb;          // Xb dead after QKV GEMM

  cast_all<<<2048, 256, 0, stream>>>(hidden, Wq, Wk, Wv, Wo, Xb, Wqb, Wkb, Wvb, Wob);

  // fused QKV: C (4096 x 6144) = X (4096x2048) * Wqkv^T, 256x192 tiles
  dim3 gq(3 * HID_ / 192, (B_ * S_) / 256);  // (32, 16) = 512 blocks = exactly 2 rounds
  gemm_qkv<<<gq, 512, 0, stream>>>(Xb, Wqb, Qb, Kb, Vtmp);

  // fused RoPE (inline trig) + V transpose: one launch, disjoint work
  rope_transpose<<<ROPE_BLOCKS_ + TRANS_BLOCKS_, 256, 0, stream>>>(Qb, Kb, pos, Vtmp, Vtb);

  dim3 ag(B_ * NH_, S_ / 64);  // bh fast, qt slow (descending inside kernel)
  attn_fused<<<ag, 256, 0, stream>>>(Qb, Kb, Vtb, Ob);

  dim3 go(HID_ / 128, (B_ * S_) / 256);  // (16, 16) = 256 blocks = exactly 1 round
  gemm_out<<<go, 512, 0, stream>>>(Ob, Wob, out);
}

// Round 10
// 386.238 us; speedup vs baseline: 1.0718x; 1.0189x over previous
//
#include <hip/hip_runtime.h>

#define B_   2
#define S_   2048
#define HID_ 2048
#define NH_  16
#define HD_  128
#define MAXTOK_ 2048

typedef float  f32x4  __attribute__((ext_vector_type(4)));
typedef __bf16 bf16x8 __attribute__((ext_vector_type(8)));
typedef unsigned short u16x8 __attribute__((ext_vector_type(8)));

__device__ __forceinline__ unsigned short f2bf(float f) {
  union { float fv; unsigned u; } v; v.fv = f;
  unsigned r = v.u + 0x7FFFu + ((v.u >> 16) & 1u);  // RNE
  return (unsigned short)(r >> 16);
}
__device__ __forceinline__ float bf2f(unsigned short h) {
  union { unsigned u; float fv; } v; v.u = ((unsigned)h) << 16;
  return v.fv;
}

// async global->LDS, 16B per lane (LDS dst must be linear/contiguous)
__device__ __forceinline__ void gload16(const void* g, void* lds) {
  __builtin_amdgcn_global_load_lds(
      (const __attribute__((address_space(1))) void*)g,
      (__attribute__((address_space(3))) void*)lds, 16, 0, 0);
}

// ---------------- fused cast fp32 -> bf16 for hidden + 4 weights ----------------
#define H4_ (B_ * S_ * HID_ / 4)
#define W4_ (HID_ * HID_ / 4)
__global__ void cast_all(const float* __restrict__ h,  const float* __restrict__ wq,
                         const float* __restrict__ wk, const float* __restrict__ wv,
                         const float* __restrict__ wo,
                         unsigned short* __restrict__ xb,  unsigned short* __restrict__ wqb,
                         unsigned short* __restrict__ wkb, unsigned short* __restrict__ wvb,
                         unsigned short* __restrict__ wob) {
  const int total = H4_ + 4 * W4_;
  int i = blockIdx.x * blockDim.x + threadIdx.x;
  int stride = gridDim.x * blockDim.x;
  for (; i < total; i += stride) {
    const float* src; unsigned short* dst; int j;
    if (i < H4_) { src = h; dst = xb; j = i; }
    else {
      int k = i - H4_, wsel = k >> 20;  // W4_ = 2^20
      j = k & (W4_ - 1);
      src = (wsel == 0) ? wq : (wsel == 1) ? wk : (wsel == 2) ? wv : wo;
      dst = (wsel == 0) ? wqb : (wsel == 1) ? wkb : (wsel == 2) ? wvb : wob;
    }
    float4 v = ((const float4*)src)[j];
    ushort4 o;
    o.x = f2bf(v.x); o.y = f2bf(v.y); o.z = f2bf(v.z); o.w = f2bf(v.w);
    ((ushort4*)dst)[j] = o;
  }
}

// ---------------- fused QKV projection: 256x192 tile, BK=64, 4-phase/K-tile ----------------
// Round-3 verified structure; round-10 change: EARLIER staging issue order
// B0,B1 | B2,A0,A2 | A1,A3 | -- with waits re-derived (oldest-k discipline):
//   vmcnt(5) end-ph1: outstanding {A1,A3(cur), B0',B1',B2',A0',A2'} = 7 ->
//     drains A1,A3 (needed by ph2's ds_reads); slack now 4 phases (was 3).
//   vmcnt(2) end-ph3: outstanding 7 -> drains oldest 5 {B0',B1',B2',A0',A2'}
//     (needed by next ph0); min slack 2 phases (was 1.5).
// Mechanism: ~12% of staged lines miss L2 (~900 cyc); larger issue-to-wait
// slack hides stragglers that stall all 8 lockstep waves at the vmcnt.
#define QKV_STG(gp, lp, rb) gload16((gp) + (size_t)(rb) * 2048, (lp) + (rb) * 64)

#define QKV_LOADA(Q) do { \
  _Pragma("unroll") \
  for (int mi_ = 0; mi_ < 2; ++mi_) { \
    const char* rp_ = (const char*)Acur + (size_t)((wm + (Q) * 32 + mi_ * 16 + rowq) * 128); \
    af[mi_][0] = *(const bf16x8*)(rp_ + cb0); \
    af[mi_][1] = *(const bf16x8*)(rp_ + cb1); \
  } } while (0)

#define QKV_LOADB() do { \
  _Pragma("unroll") \
  for (int ni_ = 0; ni_ < 3; ++ni_) { \
    const char* rp_ = (const char*)Bcur + (size_t)((wn + ni_ * 16 + rowq) * 128); \
    bfr[ni_][0] = *(const bf16x8*)(rp_ + cb0); \
    bfr[ni_][1] = *(const bf16x8*)(rp_ + cb1); \
  } } while (0)

#define QKV_MFMA(Q) do { \
  _Pragma("unroll") \
  for (int mi_ = 0; mi_ < 2; ++mi_) { \
    _Pragma("unroll") \
    for (int ni_ = 0; ni_ < 3; ++ni_) { \
      f32x4 c_ = acc[(Q) * 2 + mi_][ni_]; \
      c_ = __builtin_amdgcn_mfma_f32_16x16x32_bf16(af[mi_][0], bfr[ni_][0], c_, 0, 0, 0); \
      c_ = __builtin_amdgcn_mfma_f32_16x16x32_bf16(af[mi_][1], bfr[ni_][1], c_, 0, 0, 0); \
      acc[(Q) * 2 + mi_][ni_] = c_; \
    } } } while (0)

#define QKV_BAR    asm volatile("s_barrier" ::: "memory")
#define QKV_VMC5   asm volatile("s_waitcnt vmcnt(5)" ::: "memory")
#define QKV_VMC4   asm volatile("s_waitcnt vmcnt(4)" ::: "memory")
#define QKV_VMC2   asm volatile("s_waitcnt vmcnt(2)" ::: "memory")
#define QKV_VMC0   asm volatile("s_waitcnt vmcnt(0)" ::: "memory")

__global__ __launch_bounds__(512, 2)
void gemm_qkv(const unsigned short* __restrict__ A,
              const unsigned short* __restrict__ Bw,
              unsigned short* __restrict__ Qb,
              unsigned short* __restrict__ Kb,
              unsigned short* __restrict__ Vtmp) {
  const int K = HID_;       // 2048
  const int NT = K / 64;    // 32 K-tiles
  __shared__ __align__(16) unsigned short As[2][256 * 64];
  __shared__ __align__(16) unsigned short Bs[2][192 * 64];

  const int tid = threadIdx.x, lane = tid & 63, w = tid >> 6;
  const int n0 = blockIdx.x * 192, m0 = blockIdx.y * 256;
  const int wm = (w >> 2) * 128, wn = (w & 3) * 48;
  const int rowq = lane & 15, klane = lane >> 4;
  const int sw  = (rowq & 7) << 4;
  const int cb0 = (klane * 16) ^ sw;          // ks=0 (slots 0..3)
  const int cb1 = ((klane + 4) * 16) ^ sw;    // ks=1 (slots 4..7)
  const int srow = tid >> 3;                  // 0..63
  const int dc8  = (tid & 7) * 8;             // linear lds col (elements)
  const int scol = (((tid & 7) * 16) ^ ((srow & 7) << 4)) >> 1;  // global col (elems)

  const unsigned short* Ag = A  + (size_t)(m0 + srow) * K + scol;
  const unsigned short* Bg = Bw + (size_t)(n0 + srow) * K + scol;

  f32x4 acc[8][3];
#pragma unroll
  for (int i = 0; i < 8; ++i)
#pragma unroll
    for (int j = 0; j < 3; ++j)
#pragma unroll
      for (int r = 0; r < 4; ++r) acc[i][j][r] = 0.f;

  bf16x8 af[2][2], bfr[3][2];

  {
    unsigned short* Al = (unsigned short*)&As[0][0] + srow * 64 + dc8;
    unsigned short* Bl = (unsigned short*)&Bs[0][0] + srow * 64 + dc8;
    QKV_STG(Bg, Bl, 0); QKV_STG(Bg, Bl, 64); QKV_STG(Bg, Bl, 128);
    QKV_STG(Ag, Al, 0); QKV_STG(Ag, Al, 128);
    QKV_STG(Ag, Al, 64); QKV_STG(Ag, Al, 192);
  }
  QKV_VMC2;   // oldest 5 (B0,B1,B2,A0,A2) landed; A1,A3 outstanding (steady-state invariant)
  QKV_BAR;

  const unsigned short* Acur = &As[0][0];
  const unsigned short* Bcur = &Bs[0][0];
  unsigned short* Anx = (unsigned short*)&As[1][0];
  unsigned short* Bnx = (unsigned short*)&Bs[1][0];

  for (int t = 0; t < NT - 1; ++t) {
    const int kn = (t + 1) * 64;
    const unsigned short* Agk = Ag + kn;
    const unsigned short* Bgk = Bg + kn;
    unsigned short* Al = Anx + srow * 64 + dc8;
    unsigned short* Bl = Bnx + srow * 64 + dc8;

    // ph0: stage B0',B1'
    QKV_LOADA(0); QKV_LOADB();
    QKV_STG(Bgk, Bl, 0); QKV_STG(Bgk, Bl, 64);
    QKV_BAR;
    __builtin_amdgcn_s_setprio(1); QKV_MFMA(0); __builtin_amdgcn_s_setprio(0);
    QKV_BAR;
    // ph1: stage B2',A0',A2'; wait A1,A3 (cur, issued prev ph2 -> 4-phase slack)
    QKV_LOADA(1);
    QKV_STG(Bgk, Bl, 128); QKV_STG(Agk, Al, 0); QKV_STG(Agk, Al, 128);
    QKV_BAR;
    __builtin_amdgcn_s_setprio(1); QKV_MFMA(1); __builtin_amdgcn_s_setprio(0);
    QKV_VMC5;   // outstanding 7 -> oldest 2 (A1,A3) land
    QKV_BAR;
    // ph2: stage A1',A3'
    QKV_LOADA(2);
    QKV_STG(Agk, Al, 64); QKV_STG(Agk, Al, 192);
    QKV_BAR;
    __builtin_amdgcn_s_setprio(1); QKV_MFMA(2); __builtin_amdgcn_s_setprio(0);
    QKV_BAR;
    // ph3: no staging; wait next tile's first 5
    QKV_LOADA(3);
    QKV_BAR;
    __builtin_amdgcn_s_setprio(1); QKV_MFMA(3); __builtin_amdgcn_s_setprio(0);
    QKV_VMC2;   // outstanding 7 -> oldest 5 (B0',B1',B2',A0',A2') land
    QKV_BAR;

    { const unsigned short* tp = Acur; Acur = Anx; Anx = (unsigned short*)tp; }
    { const unsigned short* tp = Bcur; Bcur = Bnx; Bnx = (unsigned short*)tp; }
  }

  // tail tile (no staging): outstanding at entry = {A1,A3} of this tile
  QKV_LOADA(0); QKV_LOADB();
  QKV_BAR;
  __builtin_amdgcn_s_setprio(1); QKV_MFMA(0); __builtin_amdgcn_s_setprio(0);
  QKV_BAR;
  QKV_LOADA(1);
  QKV_BAR;
  __builtin_amdgcn_s_setprio(1); QKV_MFMA(1); __builtin_amdgcn_s_setprio(0);
  QKV_VMC0;   // drain A1,A3 before ph2 reads
  QKV_BAR;
  QKV_LOADA(2);
  QKV_BAR;
  __builtin_amdgcn_s_setprio(1); QKV_MFMA(2); __builtin_amdgcn_s_setprio(0);
  QKV_BAR;
  QKV_LOADA(3);
  __builtin_amdgcn_s_setprio(1); QKV_MFMA(3); __builtin_amdgcn_s_setprio(0);

  const int lr0 = klane * 4;
#pragma unroll
  for (int mi = 0; mi < 8; ++mi)
#pragma unroll
    for (int ni = 0; ni < 3; ++ni)
#pragma unroll
      for (int r = 0; r < 4; ++r) {
        int r_ = m0 + wm + mi * 16 + lr0 + r;
        int c_ = n0 + wn + ni * 16 + rowq;
        float v = acc[mi][ni][r];
        int b = r_ >> 11, s = r_ & 2047;
        int proj = c_ >> 11, cin = c_ & 2047;
        if (proj == 2) {
          Vtmp[(size_t)(b * S_ + s) * HID_ + cin] = f2bf(v);
        } else {
          int hh = cin >> 7, d = cin & 127;
          unsigned short* dst = (proj == 0) ? Qb : Kb;
          dst[(((size_t)(b * NH_ + hh) * S_ + s) * HD_) + d] = f2bf(v);
        }
      }
}

// ---------------- output projection: 256x128 tile, BK=64, 4-phase/K-tile ----------------
// Same round-10 reorder: B0,B1 | A0,A2 | A1,A3 | -- ; vmcnt(4) end-ph1
// (drains A1,A3; slack 4 phases), vmcnt(2) end-ph3 (drains B0',B1',A0',A2').
#define OUT_LOADA(Q) do { \
  _Pragma("unroll") \
  for (int mi_ = 0; mi_ < 2; ++mi_) { \
    const char* rp_ = (const char*)Acur + (size_t)((wm + (Q) * 32 + mi_ * 16 + rowq) * 128); \
    af[mi_][0] = *(const bf16x8*)(rp_ + cb0); \
    af[mi_][1] = *(const bf16x8*)(rp_ + cb1); \
  } } while (0)

#define OUT_LOADB() do { \
  _Pragma("unroll") \
  for (int ni_ = 0; ni_ < 2; ++ni_) { \
    const char* rp_ = (const char*)Bcur + (size_t)((wn + ni_ * 16 + rowq) * 128); \
    bfr[ni_][0] = *(const bf16x8*)(rp_ + cb0); \
    bfr[ni_][1] = *(const bf16x8*)(rp_ + cb1); \
  } } while (0)

#define OUT_MFMA(Q) do { \
  _Pragma("unroll") \
  for (int mi_ = 0; mi_ < 2; ++mi_) { \
    _Pragma("unroll") \
    for (int ni_ = 0; ni_ < 2; ++ni_) { \
      f32x4 c_ = acc[(Q) * 2 + mi_][ni_]; \
      c_ = __builtin_amdgcn_mfma_f32_16x16x32_bf16(af[mi_][0], bfr[ni_][0], c_, 0, 0, 0); \
      c_ = __builtin_amdgcn_mfma_f32_16x16x32_bf16(af[mi_][1], bfr[ni_][1], c_, 0, 0, 0); \
      acc[(Q) * 2 + mi_][ni_] = c_; \
    } } } while (0)

__global__ __launch_bounds__(512, 2)
void gemm_out(const unsigned short* __restrict__ A,
              const unsigned short* __restrict__ Bw,
              float* __restrict__ Cout) {
  const int K = HID_, N = HID_;
  const int NT = K / 64;    // 32
  __shared__ __align__(16) unsigned short As[2][256 * 64];
  __shared__ __align__(16) unsigned short Bs[2][128 * 64];

  const int tid = threadIdx.x, lane = tid & 63, w = tid >> 6;
  const int n0 = blockIdx.x * 128, m0 = blockIdx.y * 256;
  const int wm = (w >> 2) * 128, wn = (w & 3) * 32;
  const int rowq = lane & 15, klane = lane >> 4;
  const int sw  = (rowq & 7) << 4;
  const int cb0 = (klane * 16) ^ sw;
  const int cb1 = ((klane + 4) * 16) ^ sw;
  const int srow = tid >> 3;
  const int dc8  = (tid & 7) * 8;
  const int scol = (((tid & 7) * 16) ^ ((srow & 7) << 4)) >> 1;

  const unsigned short* Ag = A  + (size_t)(m0 + srow) * K + scol;
  const unsigned short* Bg = Bw + (size_t)(n0 + srow) * K + scol;

  f32x4 acc[8][2];
#pragma unroll
  for (int i = 0; i < 8; ++i)
#pragma unroll
    for (int j = 0; j < 2; ++j)
#pragma unroll
      for (int r = 0; r < 4; ++r) acc[i][j][r] = 0.f;

  bf16x8 af[2][2], bfr[2][2];

  {
    unsigned short* Al = (unsigned short*)&As[0][0] + srow * 64 + dc8;
    unsigned short* Bl = (unsigned short*)&Bs[0][0] + srow * 64 + dc8;
    QKV_STG(Bg, Bl, 0); QKV_STG(Bg, Bl, 64);
    QKV_STG(Ag, Al, 0); QKV_STG(Ag, Al, 128);
    QKV_STG(Ag, Al, 64); QKV_STG(Ag, Al, 192);
  }
  QKV_VMC2;   // oldest 4 (B0,B1,A0,A2) landed; A1,A3 outstanding
  QKV_BAR;

  const unsigned short* Acur = &As[0][0];
  const unsigned short* Bcur = &Bs[0][0];
  unsigned short* Anx = (unsigned short*)&As[1][0];
  unsigned short* Bnx = (unsigned short*)&Bs[1][0];

  for (int t = 0; t < NT - 1; ++t) {
    const int kn = (t + 1) * 64;
    const unsigned short* Agk = Ag + kn;
    const unsigned short* Bgk = Bg + kn;
    unsigned short* Al = Anx + srow * 64 + dc8;
    unsigned short* Bl = Bnx + srow * 64 + dc8;

    // ph0: stage B0',B1'
    OUT_LOADA(0); OUT_LOADB();
    QKV_STG(Bgk, Bl, 0); QKV_STG(Bgk, Bl, 64);
    QKV_BAR;
    __builtin_amdgcn_s_setprio(1); OUT_MFMA(0); __builtin_amdgcn_s_setprio(0);
    QKV_BAR;
    // ph1: stage A0',A2'; wait A1,A3 (cur, issued prev ph2 -> 4-phase slack)
    OUT_LOADA(1);
    QKV_STG(Agk, Al, 0); QKV_STG(Agk, Al, 128);
    QKV_BAR;
    __builtin_amdgcn_s_setprio(1); OUT_MFMA(1); __builtin_amdgcn_s_setprio(0);
    QKV_VMC4;   // outstanding 6 -> oldest 2 (A1,A3) land
    QKV_BAR;
    // ph2: stage A1',A3'
    OUT_LOADA(2);
    QKV_STG(Agk, Al, 64); QKV_STG(Agk, Al, 192);
    QKV_BAR;
    __builtin_amdgcn_s_setprio(1); OUT_MFMA(2); __builtin_amdgcn_s_setprio(0);
    QKV_BAR;
    // ph3: no staging; wait next tile's first 4
    OUT_LOADA(3);
    QKV_BAR;
    __builtin_amdgcn_s_setprio(1); OUT_MFMA(3); __builtin_amdgcn_s_setprio(0);
    QKV_VMC2;   // outstanding 6 -> oldest 4 (B0',B1',A0',A2') land
    QKV_BAR;

    { const unsigned short* tp = Acur; Acur = Anx; Anx = (unsigned short*)tp; }
    { const unsigned short* tp = Bcur; Bcur = Bnx; Bnx = (unsigned short*)tp; }
  }

  // tail (outstanding at entry: A1,A3)
  OUT_LOADA(0); OUT_LOADB();
  QKV_BAR;
  __builtin_amdgcn_s_setprio(1); OUT_MFMA(0); __builtin_amdgcn_s_setprio(0);
  QKV_BAR;
  OUT_LOADA(1);
  QKV_BAR;
  __builtin_amdgcn_s_setprio(1); OUT_MFMA(1); __builtin_amdgcn_s_setprio(0);
  QKV_VMC0;
  QKV_BAR;
  OUT_LOADA(2);
  QKV_BAR;
  __builtin_amdgcn_s_setprio(1); OUT_MFMA(2); __builtin_amdgcn_s_setprio(0);
  QKV_BAR;
  OUT_LOADA(3);
  __builtin_amdgcn_s_setprio(1); OUT_MFMA(3); __builtin_amdgcn_s_setprio(0);

  const int lr0 = klane * 4;
#pragma unroll
  for (int mi = 0; mi < 8; ++mi)
#pragma unroll
    for (int ni = 0; ni < 2; ++ni)
#pragma unroll
      for (int r = 0; r < 4; ++r) {
        int r_ = m0 + wm + mi * 16 + lr0 + r;
        int c_ = n0 + wn + ni * 16 + rowq;
        Cout[(size_t)r_ * N + c_] = acc[mi][ni][r];
      }
}

// ---------------- fused RoPE (inline trig) + V transpose ----------------
#define QSCALE_ 0.12751744f
#define ROPE_BLOCKS_ (B_ * NH_ * S_ * 8 / 256)      // 8192
#define TRANS_BLOCKS_ ((S_ / 64) * (HD_ / 64) * B_ * NH_)  // 2048
__global__ __launch_bounds__(256)
void rope_transpose(unsigned short* __restrict__ Qb, unsigned short* __restrict__ Kb,
                    const int* __restrict__ pos_ids,
                    const unsigned short* __restrict__ Vin,
                    unsigned short* __restrict__ Vt) {
  __shared__ __align__(16) unsigned short t[64 * 72];
  const int bid = blockIdx.x;
  if (bid < ROPE_BLOCKS_) {
    int i = bid * 256 + threadIdx.x;  // bhs*8 + t8
    int t8 = i & 7, bhs = i >> 3;
    int s = bhs & (S_ - 1);
    int b = bhs >> 15;  // NH_*S_ = 32768
    int d0 = t8 * 8;
    int p = pos_ids[b * S_ + s];
    float cs[8], sn[8];
#pragma unroll
    for (int j = 0; j < 8; ++j) {
      float f = __expf(-(float)(d0 + j) * (9.210340371976184f / 64.f));  // 10000^(-d/64)
      __sincosf((float)p * f, &sn[j], &cs[j]);
    }
    size_t base = (size_t)bhs * HD_ + d0;
    {
      u16x8 x1 = *(const u16x8*)(Qb + base);
      u16x8 x2 = *(const u16x8*)(Qb + base + 64);
      u16x8 o1, o2;
#pragma unroll
      for (int j = 0; j < 8; ++j) {
        float a = bf2f(x1[j]), bb = bf2f(x2[j]);
        o1[j] = f2bf((a * cs[j] - bb * sn[j]) * QSCALE_);
        o2[j] = f2bf((bb * cs[j] + a * sn[j]) * QSCALE_);
      }
      *(u16x8*)(Qb + base) = o1;
      *(u16x8*)(Qb + base + 64) = o2;
    }
    {
      u16x8 x1 = *(const u16x8*)(Kb + base);
      u16x8 x2 = *(const u16x8*)(Kb + base + 64);
      u16x8 o1, o2;
#pragma unroll
      for (int j = 0; j < 8; ++j) {
        float a = bf2f(x1[j]), bb = bf2f(x2[j]);
        o1[j] = f2bf(a * cs[j] - bb * sn[j]);
        o2[j] = f2bf(bb * cs[j] + a * sn[j]);
      }
      *(u16x8*)(Kb + base) = o1;
      *(u16x8*)(Kb + base + 64) = o2;
    }
  } else {
    int idx = bid - ROPE_BLOCKS_;
    const int s0 = (idx & 31) * 64, d0v = ((idx >> 5) & 1) * 64, bh = idx >> 6;
    const int b = bh >> 4, h = bh & 15;
    const int tid = threadIdx.x;
#pragma unroll
    for (int it = 0; it < 2; ++it) {
      int chunk = it * 256 + tid;          // 512 chunks of 8 elems
      int sl = chunk >> 3, dc = (chunk & 7) * 8;
      u16x8 v = *(const u16x8*)&Vin[(size_t)(b * S_ + s0 + sl) * HID_ + h * HD_ + d0v + dc];
      *(u16x8*)&t[sl * 72 + dc] = v;
    }
    __syncthreads();
#pragma unroll
    for (int it = 0; it < 2; ++it) {
      int lin = it * 256 + tid;
      int dl = lin & 63, sq = (lin >> 6) * 8;  // lanes span dl -> banks spread
      u16x8 v;
#pragma unroll
      for (int j = 0; j < 8; ++j) v[j] = t[(sq + j) * 72 + dl];
      *(u16x8*)&Vt[((size_t)bh * HD_ + d0v + dl) * S_ + s0 + sq] = v;
    }
  }
}

// ---------------- fused causal flash attention (v6c) ----------------
// Best-measured config (QBLK 64, 256 thr, 3 blocks/CU, setprio, defer-max).
// UNCHANGED from round 9.
#define KS_LD 136   // 64x128 K tile, padded (16B-aligned rows, 2-way bank aliasing)
#define VS_LD 72    // 128x64 V^T tile, padded
#define PS_LD 72    // 16x64 P tile per wave, padded
__global__ __launch_bounds__(256, 3)
void attn_fused(const unsigned short* __restrict__ Qb,
                const unsigned short* __restrict__ Kb,
                const unsigned short* __restrict__ Vt,
                unsigned short* __restrict__ Ob) {
  __shared__ __align__(16) unsigned short Ks[64 * KS_LD];
  __shared__ __align__(16) unsigned short Vts[128 * VS_LD];
  __shared__ __align__(16) unsigned short Ps[4 * 16 * PS_LD];

  const int tid = threadIdx.x, lane = tid & 63, w = tid >> 6;
  const int bh = blockIdx.x;                    // fast dim: spreads heads across XCDs
  const int qt = (gridDim.y - 1) - blockIdx.y;  // descending: longest blocks first (LPT)
  const int q0 = qt * 64;
  const int b = bh >> 4, h = bh & 15;
  const int rowq = lane & 15;
  const int koff = (lane >> 4) * 8;
  const int lr0 = (lane >> 4) * 4;
  const size_t qkbase = (size_t)bh * (S_ * HD_);
  const size_t vbase  = (size_t)bh * (HD_ * S_);

  bf16x8 qf0, qf1, qf2, qf3;
  {
    const unsigned short* qrow = Qb + qkbase + (size_t)(q0 + w * 16 + rowq) * HD_;
    qf0 = *(const bf16x8*)(qrow + 0 * 32 + koff);
    qf1 = *(const bf16x8*)(qrow + 1 * 32 + koff);
    qf2 = *(const bf16x8*)(qrow + 2 * 32 + koff);
    qf3 = *(const bf16x8*)(qrow + 3 * 32 + koff);
  }

  const int krow = tid >> 4, kcol = (tid & 15) * 8;  // K: 16 rows/pass
  const int vrow = tid >> 3, vcol = (tid & 7) * 8;   // V^T: 32 rows/pass
  const unsigned short* kptr = Kb + qkbase + (size_t)krow * HD_ + kcol;
  const unsigned short* vptr = Vt + vbase + (size_t)vrow * S_ + vcol;

  f32x4 oacc[8];
  for (int i = 0; i < 8; ++i)
    for (int r = 0; r < 4; ++r) oacc[i][r] = 0.f;
  float m_r[4] = {-3e38f, -3e38f, -3e38f, -3e38f};
  float l_r[4] = {0.f, 0.f, 0.f, 0.f};

  const int nkt = qt + 1;

  float4 k0, k1, k2, k3, v0, v1, v2, v3;
  k0 = *(const float4*)(kptr + 0 * 16 * HD_);
  k1 = *(const float4*)(kptr + 1 * 16 * HD_);
  k2 = *(const float4*)(kptr + 2 * 16 * HD_);
  k3 = *(const float4*)(kptr + 3 * 16 * HD_);
  v0 = *(const float4*)(vptr + 0 * 32 * S_);
  v1 = *(const float4*)(vptr + 1 * 32 * S_);
  v2 = *(const float4*)(vptr + 2 * 32 * S_);
  v3 = *(const float4*)(vptr + 3 * 32 * S_);

  for (int kt = 0; kt < nkt; ++kt) {
    __syncthreads();  // previous tile's readers done
    *(float4*)&Ks[(krow + 0 * 16) * KS_LD + kcol] = k0;
    *(float4*)&Ks[(krow + 1 * 16) * KS_LD + kcol] = k1;
    *(float4*)&Ks[(krow + 2 * 16) * KS_LD + kcol] = k2;
    *(float4*)&Ks[(krow + 3 * 16) * KS_LD + kcol] = k3;
    *(float4*)&Vts[(vrow + 0 * 32) * VS_LD + vcol] = v0;
    *(float4*)&Vts[(vrow + 1 * 32) * VS_LD + vcol] = v1;
    *(float4*)&Vts[(vrow + 2 * 32) * VS_LD + vcol] = v2;
    *(float4*)&Vts[(vrow + 3 * 32) * VS_LD + vcol] = v3;
    if (kt + 1 < nkt) {
      const unsigned short* kp = kptr + (size_t)(kt + 1) * 64 * HD_;
      k0 = *(const float4*)(kp + 0 * 16 * HD_);
      k1 = *(const float4*)(kp + 1 * 16 * HD_);
      k2 = *(const float4*)(kp + 2 * 16 * HD_);
      k3 = *(const float4*)(kp + 3 * 16 * HD_);
    }
    __syncthreads();

    f32x4 sacc[4];
    for (int n = 0; n < 4; ++n)
      for (int r = 0; r < 4; ++r) sacc[n][r] = 0.f;
    __builtin_amdgcn_s_setprio(1);
#pragma unroll
    for (int n = 0; n < 4; ++n) {
      const unsigned short* krow_p = &Ks[(n * 16 + rowq) * KS_LD + koff];
      sacc[n] = __builtin_amdgcn_mfma_f32_16x16x32_bf16(qf0, *(const bf16x8*)(krow_p + 0 * 32), sacc[n], 0, 0, 0);
      sacc[n] = __builtin_amdgcn_mfma_f32_16x16x32_bf16(qf1, *(const bf16x8*)(krow_p + 1 * 32), sacc[n], 0, 0, 0);
      sacc[n] = __builtin_amdgcn_mfma_f32_16x16x32_bf16(qf2, *(const bf16x8*)(krow_p + 2 * 32), sacc[n], 0, 0, 0);
      sacc[n] = __builtin_amdgcn_mfma_f32_16x16x32_bf16(qf3, *(const bf16x8*)(krow_p + 3 * 32), sacc[n], 0, 0, 0);
    }
    __builtin_amdgcn_s_setprio(0);

    float tmax[4] = {-3e38f, -3e38f, -3e38f, -3e38f};
    if (kt == qt) {
      for (int n = 0; n < 4; ++n) {
        int col = n * 16 + rowq;
        for (int r = 0; r < 4; ++r) {
          int row = w * 16 + lr0 + r;
          float x = (col <= row) ? sacc[n][r] : -1e30f;
          sacc[n][r] = x;
          tmax[r] = fmaxf(tmax[r], x);
        }
      }
    } else {
      for (int n = 0; n < 4; ++n)
        for (int r = 0; r < 4; ++r)
          tmax[r] = fmaxf(tmax[r], sacc[n][r]);
    }
    for (int off = 1; off < 16; off <<= 1)
      for (int r = 0; r < 4; ++r) tmax[r] = fmaxf(tmax[r], __shfl_xor(tmax[r], off));

    // T13 defer-max: rescale only if some row's max grew by >8 (exp2 units)
    float ex = -1.f;
    for (int r = 0; r < 4; ++r) ex = fmaxf(ex, tmax[r] - m_r[r]);
    if (__any(ex > 8.f)) {
      for (int r = 0; r < 4; ++r) {
        float mn = fmaxf(m_r[r], tmax[r]);
        float a = __builtin_amdgcn_exp2f(m_r[r] - mn);
        m_r[r] = mn;
        l_r[r] *= a;
        for (int nd = 0; nd < 8; ++nd) oacc[nd][r] *= a;
      }
    }
    float rs[4] = {0.f, 0.f, 0.f, 0.f};
    for (int n = 0; n < 4; ++n)
      for (int r = 0; r < 4; ++r) {
        float p = __builtin_amdgcn_exp2f(sacc[n][r] - m_r[r]);
        sacc[n][r] = p;
        rs[r] += p;
      }
    for (int off = 1; off < 16; off <<= 1)
      for (int r = 0; r < 4; ++r) rs[r] += __shfl_xor(rs[r], off);
    for (int r = 0; r < 4; ++r) l_r[r] += rs[r];

    if (kt + 1 < nkt) {
      const unsigned short* vp = vptr + (size_t)(kt + 1) * 64;
      v0 = *(const float4*)(vp + 0 * 32 * S_);
      v1 = *(const float4*)(vp + 1 * 32 * S_);
      v2 = *(const float4*)(vp + 2 * 32 * S_);
      v3 = *(const float4*)(vp + 3 * 32 * S_);
    }

    unsigned short* pw = &Ps[w * 16 * PS_LD];
    for (int n = 0; n < 4; ++n)
      for (int r = 0; r < 4; ++r)
        pw[(lr0 + r) * PS_LD + n * 16 + rowq] = f2bf(sacc[n][r]);

    __builtin_amdgcn_s_setprio(1);
#pragma unroll
    for (int t2 = 0; t2 < 2; ++t2) {
      bf16x8 pa = *(const bf16x8*)&pw[rowq * PS_LD + t2 * 32 + koff];
      for (int nd = 0; nd < 8; ++nd) {
        bf16x8 vb = *(const bf16x8*)&Vts[(nd * 16 + rowq) * VS_LD + t2 * 32 + koff];
        oacc[nd] = __builtin_amdgcn_mfma_f32_16x16x32_bf16(pa, vb, oacc[nd], 0, 0, 0);
      }
    }
    __builtin_amdgcn_s_setprio(0);
  }

  float linv[4];
  for (int r = 0; r < 4; ++r) linv[r] = __builtin_amdgcn_rcpf(l_r[r]);
  for (int nd = 0; nd < 8; ++nd) {
    int col = h * HD_ + nd * 16 + rowq;
    for (int r = 0; r < 4; ++r) {
      int row = q0 + w * 16 + lr0 + r;
      Ob[(size_t)(b * S_ + row) * HID_ + col] = f2bf(oacc[nd][r] * linv[r]);
    }
  }
}

// ---------------- launcher ----------------
extern "C" void kernel_launch(void* const* d_in, const int* in_sizes, int n_in,
                              void* d_out, int out_size, void* d_ws, size_t ws_size,
                              hipStream_t stream) {
  (void)in_sizes; (void)n_in; (void)out_size; (void)ws_size;
  const float* hidden = (const float*)d_in[0];
  // d_in[1] = attention_mask (causal; reproduced analytically)
  const int* pos = (const int*)d_in[2];
  const float* Wq = (const float*)d_in[3];
  const float* Wk = (const float*)d_in[4];
  const float* Wv = (const float*)d_in[5];
  const float* Wo = (const float*)d_in[6];
  float* out = (float*)d_out;

  char* ws = (char*)d_ws;
  unsigned short* Xb   = (unsigned short*)(ws);               // 16 MB  (B,S,HID) bf16
  unsigned short* Wqb  = (unsigned short*)(ws + 16777216);    // 8 MB  Wq -- Wqb/Wkb/Wvb contiguous:
  unsigned short* Wkb  = (unsigned short*)(ws + 25165824);    // 8 MB  Wk -- one (6144,2048) QKV weight
  unsigned short* Wvb  = (unsigned short*)(ws + 33554432);    // 8 MB  Wv
  unsigned short* Wob  = (unsigned short*)(ws + 41943040);    // 8 MB
  unsigned short* Qb   = (unsigned short*)(ws + 50331648);    // 16 MB (B,NH,S,HD)
  unsigned short* Kb   = (unsigned short*)(ws + 67108864);    // 16 MB
  unsigned short* Vtmp = (unsigned short*)(ws + 83886080);    // 16 MB (B,S,HID)
  unsigned short* Vtb  = (unsigned short*)(ws + 100663296);   // 16 MB (B,NH,HD,S)
  unsigned short* Ob   = Xb;          // Xb dead after QKV GEMM

  cast_all<<<2048, 256, 0, stream>>>(hidden, Wq, Wk, Wv, Wo, Xb, Wqb, Wkb, Wvb, Wob);

  // fused QKV: C (4096 x 6144) = X (4096x2048) * Wqkv^T, 256x192 tiles
  dim3 gq(3 * HID_ / 192, (B_ * S_) / 256);  // (32, 16) = 512 blocks = exactly 2 rounds
  gemm_qkv<<<gq, 512, 0, stream>>>(Xb, Wqb, Qb, Kb, Vtmp);

  // fused RoPE (inline trig) + V transpose: one launch, disjoint work
  rope_transpose<<<ROPE_BLOCKS_ + TRANS_BLOCKS_, 256, 0, stream>>>(Qb, Kb, pos, Vtmp, Vtb);

  dim3 ag(B_ * NH_, S_ / 64);  // bh fast, qt slow (descending inside kernel)
  attn_fused<<<ag, 256, 0, stream>>>(Qb, Kb, Vtb, Ob);

  dim3 go(HID_ / 128, (B_ * S_) / 256);  // (16, 16) = 256 blocks = exactly 1 round
  gemm_out<<<go, 512, 0, stream>>>(Ob, Wob, out);
}

// Round 11
// 383.076 us; speedup vs baseline: 1.0806x; 1.0083x over previous
//
#include <hip/hip_runtime.h>

#define B_   2
#define S_   2048
#define HID_ 2048
#define NH_  16
#define HD_  128
#define MAXTOK_ 2048

typedef float  f32x4  __attribute__((ext_vector_type(4)));
typedef __bf16 bf16x8 __attribute__((ext_vector_type(8)));
typedef unsigned short u16x8 __attribute__((ext_vector_type(8)));

__device__ __forceinline__ unsigned short f2bf(float f) {
  union { float fv; unsigned u; } v; v.fv = f;
  unsigned r = v.u + 0x7FFFu + ((v.u >> 16) & 1u);  // RNE
  return (unsigned short)(r >> 16);
}
__device__ __forceinline__ float bf2f(unsigned short h) {
  union { unsigned u; float fv; } v; v.u = ((unsigned)h) << 16;
  return v.fv;
}

// async global->LDS, 16B per lane (LDS dst must be linear/contiguous)
__device__ __forceinline__ void gload16(const void* g, void* lds) {
  __builtin_amdgcn_global_load_lds(
      (const __attribute__((address_space(1))) void*)g,
      (__attribute__((address_space(3))) void*)lds, 16, 0, 0);
}

// ---------------- fused cast fp32 -> bf16 for hidden + 4 weights ----------------
#define H4_ (B_ * S_ * HID_ / 4)
#define W4_ (HID_ * HID_ / 4)
__global__ void cast_all(const float* __restrict__ h,  const float* __restrict__ wq,
                         const float* __restrict__ wk, const float* __restrict__ wv,
                         const float* __restrict__ wo,
                         unsigned short* __restrict__ xb,  unsigned short* __restrict__ wqb,
                         unsigned short* __restrict__ wkb, unsigned short* __restrict__ wvb,
                         unsigned short* __restrict__ wob) {
  const int total = H4_ + 4 * W4_;
  int i = blockIdx.x * blockDim.x + threadIdx.x;
  int stride = gridDim.x * blockDim.x;
  for (; i < total; i += stride) {
    const float* src; unsigned short* dst; int j;
    if (i < H4_) { src = h; dst = xb; j = i; }
    else {
      int k = i - H4_, wsel = k >> 20;  // W4_ = 2^20
      j = k & (W4_ - 1);
      src = (wsel == 0) ? wq : (wsel == 1) ? wk : (wsel == 2) ? wv : wo;
      dst = (wsel == 0) ? wqb : (wsel == 1) ? wkb : (wsel == 2) ? wvb : wob;
    }
    float4 v = ((const float4*)src)[j];
    ushort4 o;
    o.x = f2bf(v.x); o.y = f2bf(v.y); o.z = f2bf(v.z); o.w = f2bf(v.w);
    ((ushort4*)dst)[j] = o;
  }
}

// ---------------- fused QKV projection: 256x192 tile, BK=64, 4-phase/K-tile ----------------
// REVERTED to round-8 exact staging order (verified 107.3-107.6 us, MfmaUtil
// 40.5%, conflicts 0 across 4 runs): B0,B1 | B2,A0 | A2,A1 | A3 with
// vmcnt(4) end-ph1, vmcnt(2) end-ph3. Round-10's front-loaded order
// (B2,A0,A2 all in ph1) measured WORSE (MfmaUtil 39.3) -> per-phase issue
// balance beats raw issue-to-wait slack in this skeleton.
#define QKV_STG(gp, lp, rb) gload16((gp) + (size_t)(rb) * 2048, (lp) + (rb) * 64)

#define QKV_LOADA(Q) do { \
  _Pragma("unroll") \
  for (int mi_ = 0; mi_ < 2; ++mi_) { \
    const char* rp_ = (const char*)Acur + (size_t)((wm + (Q) * 32 + mi_ * 16 + rowq) * 128); \
    af[mi_][0] = *(const bf16x8*)(rp_ + cb0); \
    af[mi_][1] = *(const bf16x8*)(rp_ + cb1); \
  } } while (0)

#define QKV_LOADB() do { \
  _Pragma("unroll") \
  for (int ni_ = 0; ni_ < 3; ++ni_) { \
    const char* rp_ = (const char*)Bcur + (size_t)((wn + ni_ * 16 + rowq) * 128); \
    bfr[ni_][0] = *(const bf16x8*)(rp_ + cb0); \
    bfr[ni_][1] = *(const bf16x8*)(rp_ + cb1); \
  } } while (0)

#define QKV_MFMA(Q) do { \
  _Pragma("unroll") \
  for (int mi_ = 0; mi_ < 2; ++mi_) { \
    _Pragma("unroll") \
    for (int ni_ = 0; ni_ < 3; ++ni_) { \
      f32x4 c_ = acc[(Q) * 2 + mi_][ni_]; \
      c_ = __builtin_amdgcn_mfma_f32_16x16x32_bf16(af[mi_][0], bfr[ni_][0], c_, 0, 0, 0); \
      c_ = __builtin_amdgcn_mfma_f32_16x16x32_bf16(af[mi_][1], bfr[ni_][1], c_, 0, 0, 0); \
      acc[(Q) * 2 + mi_][ni_] = c_; \
    } } } while (0)

#define QKV_BAR    asm volatile("s_barrier" ::: "memory")
#define QKV_VMC4   asm volatile("s_waitcnt vmcnt(4)" ::: "memory")
#define QKV_VMC2   asm volatile("s_waitcnt vmcnt(2)" ::: "memory")
#define QKV_VMC0   asm volatile("s_waitcnt vmcnt(0)" ::: "memory")

__global__ __launch_bounds__(512, 2)
void gemm_qkv(const unsigned short* __restrict__ A,
              const unsigned short* __restrict__ Bw,
              unsigned short* __restrict__ Qb,
              unsigned short* __restrict__ Kb,
              unsigned short* __restrict__ Vtmp) {
  const int K = HID_;       // 2048
  const int NT = K / 64;    // 32 K-tiles
  __shared__ __align__(16) unsigned short As[2][256 * 64];
  __shared__ __align__(16) unsigned short Bs[2][192 * 64];

  const int tid = threadIdx.x, lane = tid & 63, w = tid >> 6;
  const int n0 = blockIdx.x * 192, m0 = blockIdx.y * 256;
  const int wm = (w >> 2) * 128, wn = (w & 3) * 48;
  const int rowq = lane & 15, klane = lane >> 4;
  const int sw  = (rowq & 7) << 4;
  const int cb0 = (klane * 16) ^ sw;          // ks=0 (slots 0..3)
  const int cb1 = ((klane + 4) * 16) ^ sw;    // ks=1 (slots 4..7)
  const int srow = tid >> 3;                  // 0..63
  const int dc8  = (tid & 7) * 8;             // linear lds col (elements)
  const int scol = (((tid & 7) * 16) ^ ((srow & 7) << 4)) >> 1;  // global col (elems)

  const unsigned short* Ag = A  + (size_t)(m0 + srow) * K + scol;
  const unsigned short* Bg = Bw + (size_t)(n0 + srow) * K + scol;

  f32x4 acc[8][3];
#pragma unroll
  for (int i = 0; i < 8; ++i)
#pragma unroll
    for (int j = 0; j < 3; ++j)
#pragma unroll
      for (int r = 0; r < 4; ++r) acc[i][j][r] = 0.f;

  bf16x8 af[2][2], bfr[3][2];

  {
    unsigned short* Al = (unsigned short*)&As[0][0] + srow * 64 + dc8;
    unsigned short* Bl = (unsigned short*)&Bs[0][0] + srow * 64 + dc8;
    QKV_STG(Bg, Bl, 0); QKV_STG(Bg, Bl, 64); QKV_STG(Bg, Bl, 128);
    QKV_STG(Ag, Al, 0); QKV_STG(Ag, Al, 128);
    QKV_STG(Ag, Al, 64); QKV_STG(Ag, Al, 192);
  }
  QKV_VMC2;   // oldest 5 (B0,B1,B2,A0,A2) landed
  QKV_BAR;

  const unsigned short* Acur = &As[0][0];
  const unsigned short* Bcur = &Bs[0][0];
  unsigned short* Anx = (unsigned short*)&As[1][0];
  unsigned short* Bnx = (unsigned short*)&Bs[1][0];

  for (int t = 0; t < NT - 1; ++t) {
    const int kn = (t + 1) * 64;
    const unsigned short* Agk = Ag + kn;
    const unsigned short* Bgk = Bg + kn;
    unsigned short* Al = Anx + srow * 64 + dc8;
    unsigned short* Bl = Bnx + srow * 64 + dc8;

    QKV_LOADA(0); QKV_LOADB();
    QKV_STG(Bgk, Bl, 0); QKV_STG(Bgk, Bl, 64);
    QKV_BAR;
    __builtin_amdgcn_s_setprio(1); QKV_MFMA(0); __builtin_amdgcn_s_setprio(0);
    QKV_BAR;
    QKV_LOADA(1);
    QKV_STG(Bgk, Bl, 128); QKV_STG(Agk, Al, 0);
    QKV_BAR;
    __builtin_amdgcn_s_setprio(1); QKV_MFMA(1); __builtin_amdgcn_s_setprio(0);
    QKV_VMC4;
    QKV_BAR;
    QKV_LOADA(2);
    QKV_STG(Agk, Al, 128); QKV_STG(Agk, Al, 64);
    QKV_BAR;
    __builtin_amdgcn_s_setprio(1); QKV_MFMA(2); __builtin_amdgcn_s_setprio(0);
    QKV_BAR;
    QKV_LOADA(3);
    QKV_STG(Agk, Al, 192);
    QKV_BAR;
    __builtin_amdgcn_s_setprio(1); QKV_MFMA(3); __builtin_amdgcn_s_setprio(0);
    QKV_VMC2;
    QKV_BAR;

    { const unsigned short* tp = Acur; Acur = Anx; Anx = (unsigned short*)tp; }
    { const unsigned short* tp = Bcur; Bcur = Bnx; Bnx = (unsigned short*)tp; }
  }

  QKV_LOADA(0); QKV_LOADB();
  QKV_BAR;
  __builtin_amdgcn_s_setprio(1); QKV_MFMA(0); __builtin_amdgcn_s_setprio(0);
  QKV_BAR;
  QKV_LOADA(1);
  QKV_BAR;
  __builtin_amdgcn_s_setprio(1); QKV_MFMA(1); __builtin_amdgcn_s_setprio(0);
  QKV_VMC0;
  QKV_BAR;
  QKV_LOADA(2);
  QKV_BAR;
  __builtin_amdgcn_s_setprio(1); QKV_MFMA(2); __builtin_amdgcn_s_setprio(0);
  QKV_BAR;
  QKV_LOADA(3);
  __builtin_amdgcn_s_setprio(1); QKV_MFMA(3); __builtin_amdgcn_s_setprio(0);

  const int lr0 = klane * 4;
#pragma unroll
  for (int mi = 0; mi < 8; ++mi)
#pragma unroll
    for (int ni = 0; ni < 3; ++ni)
#pragma unroll
      for (int r = 0; r < 4; ++r) {
        int r_ = m0 + wm + mi * 16 + lr0 + r;
        int c_ = n0 + wn + ni * 16 + rowq;
        float v = acc[mi][ni][r];
        int b = r_ >> 11, s = r_ & 2047;
        int proj = c_ >> 11, cin = c_ & 2047;
        if (proj == 2) {
          Vtmp[(size_t)(b * S_ + s) * HID_ + cin] = f2bf(v);
        } else {
          int hh = cin >> 7, d = cin & 127;
          unsigned short* dst = (proj == 0) ? Qb : Kb;
          dst[(((size_t)(b * NH_ + hh) * S_ + s) * HD_) + d] = f2bf(v);
        }
      }
}

// ---------------- output projection: 256x128 tile, BK=64, 4-phase/K-tile ----------------
// Round-10 order KEPT (part of the 386.2 best): B0,B1 | A0,A2 | A1,A3 | --
// vmcnt(4) end-ph1 (drains A1,A3), vmcnt(2) end-ph3 (drains B0',B1',A0',A2').
#define OUT_LOADA(Q) do { \
  _Pragma("unroll") \
  for (int mi_ = 0; mi_ < 2; ++mi_) { \
    const char* rp_ = (const char*)Acur + (size_t)((wm + (Q) * 32 + mi_ * 16 + rowq) * 128); \
    af[mi_][0] = *(const bf16x8*)(rp_ + cb0); \
    af[mi_][1] = *(const bf16x8*)(rp_ + cb1); \
  } } while (0)

#define OUT_LOADB() do { \
  _Pragma("unroll") \
  for (int ni_ = 0; ni_ < 2; ++ni_) { \
    const char* rp_ = (const char*)Bcur + (size_t)((wn + ni_ * 16 + rowq) * 128); \
    bfr[ni_][0] = *(const bf16x8*)(rp_ + cb0); \
    bfr[ni_][1] = *(const bf16x8*)(rp_ + cb1); \
  } } while (0)

#define OUT_MFMA(Q) do { \
  _Pragma("unroll") \
  for (int mi_ = 0; mi_ < 2; ++mi_) { \
    _Pragma("unroll") \
    for (int ni_ = 0; ni_ < 2; ++ni_) { \
      f32x4 c_ = acc[(Q) * 2 + mi_][ni_]; \
      c_ = __builtin_amdgcn_mfma_f32_16x16x32_bf16(af[mi_][0], bfr[ni_][0], c_, 0, 0, 0); \
      c_ = __builtin_amdgcn_mfma_f32_16x16x32_bf16(af[mi_][1], bfr[ni_][1], c_, 0, 0, 0); \
      acc[(Q) * 2 + mi_][ni_] = c_; \
    } } } while (0)

__global__ __launch_bounds__(512, 2)
void gemm_out(const unsigned short* __restrict__ A,
              const unsigned short* __restrict__ Bw,
              float* __restrict__ Cout) {
  const int K = HID_, N = HID_;
  const int NT = K / 64;    // 32
  __shared__ __align__(16) unsigned short As[2][256 * 64];
  __shared__ __align__(16) unsigned short Bs[2][128 * 64];

  const int tid = threadIdx.x, lane = tid & 63, w = tid >> 6;
  const int n0 = blockIdx.x * 128, m0 = blockIdx.y * 256;
  const int wm = (w >> 2) * 128, wn = (w & 3) * 32;
  const int rowq = lane & 15, klane = lane >> 4;
  const int sw  = (rowq & 7) << 4;
  const int cb0 = (klane * 16) ^ sw;
  const int cb1 = ((klane + 4) * 16) ^ sw;
  const int srow = tid >> 3;
  const int dc8  = (tid & 7) * 8;
  const int scol = (((tid & 7) * 16) ^ ((srow & 7) << 4)) >> 1;

  const unsigned short* Ag = A  + (size_t)(m0 + srow) * K + scol;
  const unsigned short* Bg = Bw + (size_t)(n0 + srow) * K + scol;

  f32x4 acc[8][2];
#pragma unroll
  for (int i = 0; i < 8; ++i)
#pragma unroll
    for (int j = 0; j < 2; ++j)
#pragma unroll
      for (int r = 0; r < 4; ++r) acc[i][j][r] = 0.f;

  bf16x8 af[2][2], bfr[2][2];

  {
    unsigned short* Al = (unsigned short*)&As[0][0] + srow * 64 + dc8;
    unsigned short* Bl = (unsigned short*)&Bs[0][0] + srow * 64 + dc8;
    QKV_STG(Bg, Bl, 0); QKV_STG(Bg, Bl, 64);
    QKV_STG(Ag, Al, 0); QKV_STG(Ag, Al, 128);
    QKV_STG(Ag, Al, 64); QKV_STG(Ag, Al, 192);
  }
  QKV_VMC2;   // oldest 4 (B0,B1,A0,A2) landed; A1,A3 outstanding
  QKV_BAR;

  const unsigned short* Acur = &As[0][0];
  const unsigned short* Bcur = &Bs[0][0];
  unsigned short* Anx = (unsigned short*)&As[1][0];
  unsigned short* Bnx = (unsigned short*)&Bs[1][0];

  for (int t = 0; t < NT - 1; ++t) {
    const int kn = (t + 1) * 64;
    const unsigned short* Agk = Ag + kn;
    const unsigned short* Bgk = Bg + kn;
    unsigned short* Al = Anx + srow * 64 + dc8;
    unsigned short* Bl = Bnx + srow * 64 + dc8;

    // ph0: stage B0',B1'
    OUT_LOADA(0); OUT_LOADB();
    QKV_STG(Bgk, Bl, 0); QKV_STG(Bgk, Bl, 64);
    QKV_BAR;
    __builtin_amdgcn_s_setprio(1); OUT_MFMA(0); __builtin_amdgcn_s_setprio(0);
    QKV_BAR;
    // ph1: stage A0',A2'; wait A1,A3 (cur)
    OUT_LOADA(1);
    QKV_STG(Agk, Al, 0); QKV_STG(Agk, Al, 128);
    QKV_BAR;
    __builtin_amdgcn_s_setprio(1); OUT_MFMA(1); __builtin_amdgcn_s_setprio(0);
    QKV_VMC4;   // outstanding 6 -> oldest 2 (A1,A3) land
    QKV_BAR;
    // ph2: stage A1',A3'
    OUT_LOADA(2);
    QKV_STG(Agk, Al, 64); QKV_STG(Agk, Al, 192);
    QKV_BAR;
    __builtin_amdgcn_s_setprio(1); OUT_MFMA(2); __builtin_amdgcn_s_setprio(0);
    QKV_BAR;
    // ph3: no staging; wait next tile's first 4
    OUT_LOADA(3);
    QKV_BAR;
    __builtin_amdgcn_s_setprio(1); OUT_MFMA(3); __builtin_amdgcn_s_setprio(0);
    QKV_VMC2;   // outstanding 6 -> oldest 4 (B0',B1',A0',A2') land
    QKV_BAR;

    { const unsigned short* tp = Acur; Acur = Anx; Anx = (unsigned short*)tp; }
    { const unsigned short* tp = Bcur; Bcur = Bnx; Bnx = (unsigned short*)tp; }
  }

  // tail (outstanding at entry: A1,A3)
  OUT_LOADA(0); OUT_LOADB();
  QKV_BAR;
  __builtin_amdgcn_s_setprio(1); OUT_MFMA(0); __builtin_amdgcn_s_setprio(0);
  QKV_BAR;
  OUT_LOADA(1);
  QKV_BAR;
  __builtin_amdgcn_s_setprio(1); OUT_MFMA(1); __builtin_amdgcn_s_setprio(0);
  QKV_VMC0;
  QKV_BAR;
  OUT_LOADA(2);
  QKV_BAR;
  __builtin_amdgcn_s_setprio(1); OUT_MFMA(2); __builtin_amdgcn_s_setprio(0);
  QKV_BAR;
  OUT_LOADA(3);
  __builtin_amdgcn_s_setprio(1); OUT_MFMA(3); __builtin_amdgcn_s_setprio(0);

  const int lr0 = klane * 4;
#pragma unroll
  for (int mi = 0; mi < 8; ++mi)
#pragma unroll
    for (int ni = 0; ni < 2; ++ni)
#pragma unroll
      for (int r = 0; r < 4; ++r) {
        int r_ = m0 + wm + mi * 16 + lr0 + r;
        int c_ = n0 + wn + ni * 16 + rowq;
        Cout[(size_t)r_ * N + c_] = acc[mi][ni][r];
      }
}

// ---------------- fused RoPE (inline trig) + V transpose ----------------
#define QSCALE_ 0.12751744f
#define ROPE_BLOCKS_ (B_ * NH_ * S_ * 8 / 256)      // 8192
#define TRANS_BLOCKS_ ((S_ / 64) * (HD_ / 64) * B_ * NH_)  // 2048
__global__ __launch_bounds__(256)
void rope_transpose(unsigned short* __restrict__ Qb, unsigned short* __restrict__ Kb,
                    const int* __restrict__ pos_ids,
                    const unsigned short* __restrict__ Vin,
                    unsigned short* __restrict__ Vt) {
  __shared__ __align__(16) unsigned short t[64 * 72];
  const int bid = blockIdx.x;
  if (bid < ROPE_BLOCKS_) {
    int i = bid * 256 + threadIdx.x;  // bhs*8 + t8
    int t8 = i & 7, bhs = i >> 3;
    int s = bhs & (S_ - 1);
    int b = bhs >> 15;  // NH_*S_ = 32768
    int d0 = t8 * 8;
    int p = pos_ids[b * S_ + s];
    float cs[8], sn[8];
#pragma unroll
    for (int j = 0; j < 8; ++j) {
      float f = __expf(-(float)(d0 + j) * (9.210340371976184f / 64.f));  // 10000^(-d/64)
      __sincosf((float)p * f, &sn[j], &cs[j]);
    }
    size_t base = (size_t)bhs * HD_ + d0;
    {
      u16x8 x1 = *(const u16x8*)(Qb + base);
      u16x8 x2 = *(const u16x8*)(Qb + base + 64);
      u16x8 o1, o2;
#pragma unroll
      for (int j = 0; j < 8; ++j) {
        float a = bf2f(x1[j]), bb = bf2f(x2[j]);
        o1[j] = f2bf((a * cs[j] - bb * sn[j]) * QSCALE_);
        o2[j] = f2bf((bb * cs[j] + a * sn[j]) * QSCALE_);
      }
      *(u16x8*)(Qb + base) = o1;
      *(u16x8*)(Qb + base + 64) = o2;
    }
    {
      u16x8 x1 = *(const u16x8*)(Kb + base);
      u16x8 x2 = *(const u16x8*)(Kb + base + 64);
      u16x8 o1, o2;
#pragma unroll
      for (int j = 0; j < 8; ++j) {
        float a = bf2f(x1[j]), bb = bf2f(x2[j]);
        o1[j] = f2bf(a * cs[j] - bb * sn[j]);
        o2[j] = f2bf(bb * cs[j] + a * sn[j]);
      }
      *(u16x8*)(Kb + base) = o1;
      *(u16x8*)(Kb + base + 64) = o2;
    }
  } else {
    int idx = bid - ROPE_BLOCKS_;
    const int s0 = (idx & 31) * 64, d0v = ((idx >> 5) & 1) * 64, bh = idx >> 6;
    const int b = bh >> 4, h = bh & 15;
    const int tid = threadIdx.x;
#pragma unroll
    for (int it = 0; it < 2; ++it) {
      int chunk = it * 256 + tid;          // 512 chunks of 8 elems
      int sl = chunk >> 3, dc = (chunk & 7) * 8;
      u16x8 v = *(const u16x8*)&Vin[(size_t)(b * S_ + s0 + sl) * HID_ + h * HD_ + d0v + dc];
      *(u16x8*)&t[sl * 72 + dc] = v;
    }
    __syncthreads();
#pragma unroll
    for (int it = 0; it < 2; ++it) {
      int lin = it * 256 + tid;
      int dl = lin & 63, sq = (lin >> 6) * 8;  // lanes span dl -> banks spread
      u16x8 v;
#pragma unroll
      for (int j = 0; j < 8; ++j) v[j] = t[(sq + j) * 72 + dl];
      *(u16x8*)&Vt[((size_t)bh * HD_ + d0v + dl) * S_ + s0 + sq] = v;
    }
  }
}

// ---------------- fused causal flash attention (v6c) ----------------
// Best-measured config (QBLK 64, 256 thr, 3 blocks/CU, setprio, defer-max).
// UNCHANGED from round 10.
#define KS_LD 136   // 64x128 K tile, padded (16B-aligned rows, 2-way bank aliasing)
#define VS_LD 72    // 128x64 V^T tile, padded
#define PS_LD 72    // 16x64 P tile per wave, padded
__global__ __launch_bounds__(256, 3)
void attn_fused(const unsigned short* __restrict__ Qb,
                const unsigned short* __restrict__ Kb,
                const unsigned short* __restrict__ Vt,
                unsigned short* __restrict__ Ob) {
  __shared__ __align__(16) unsigned short Ks[64 * KS_LD];
  __shared__ __align__(16) unsigned short Vts[128 * VS_LD];
  __shared__ __align__(16) unsigned short Ps[4 * 16 * PS_LD];

  const int tid = threadIdx.x, lane = tid & 63, w = tid >> 6;
  const int bh = blockIdx.x;                    // fast dim: spreads heads across XCDs
  const int qt = (gridDim.y - 1) - blockIdx.y;  // descending: longest blocks first (LPT)
  const int q0 = qt * 64;
  const int b = bh >> 4, h = bh & 15;
  const int rowq = lane & 15;
  const int koff = (lane >> 4) * 8;
  const int lr0 = (lane >> 4) * 4;
  const size_t qkbase = (size_t)bh * (S_ * HD_);
  const size_t vbase  = (size_t)bh * (HD_ * S_);

  bf16x8 qf0, qf1, qf2, qf3;
  {
    const unsigned short* qrow = Qb + qkbase + (size_t)(q0 + w * 16 + rowq) * HD_;
    qf0 = *(const bf16x8*)(qrow + 0 * 32 + koff);
    qf1 = *(const bf16x8*)(qrow + 1 * 32 + koff);
    qf2 = *(const bf16x8*)(qrow + 2 * 32 + koff);
    qf3 = *(const bf16x8*)(qrow + 3 * 32 + koff);
  }

  const int krow = tid >> 4, kcol = (tid & 15) * 8;  // K: 16 rows/pass
  const int vrow = tid >> 3, vcol = (tid & 7) * 8;   // V^T: 32 rows/pass
  const unsigned short* kptr = Kb + qkbase + (size_t)krow * HD_ + kcol;
  const unsigned short* vptr = Vt + vbase + (size_t)vrow * S_ + vcol;

  f32x4 oacc[8];
  for (int i = 0; i < 8; ++i)
    for (int r = 0; r < 4; ++r) oacc[i][r] = 0.f;
  float m_r[4] = {-3e38f, -3e38f, -3e38f, -3e38f};
  float l_r[4] = {0.f, 0.f, 0.f, 0.f};

  const int nkt = qt + 1;

  float4 k0, k1, k2, k3, v0, v1, v2, v3;
  k0 = *(const float4*)(kptr + 0 * 16 * HD_);
  k1 = *(const float4*)(kptr + 1 * 16 * HD_);
  k2 = *(const float4*)(kptr + 2 * 16 * HD_);
  k3 = *(const float4*)(kptr + 3 * 16 * HD_);
  v0 = *(const float4*)(vptr + 0 * 32 * S_);
  v1 = *(const float4*)(vptr + 1 * 32 * S_);
  v2 = *(const float4*)(vptr + 2 * 32 * S_);
  v3 = *(const float4*)(vptr + 3 * 32 * S_);

  for (int kt = 0; kt < nkt; ++kt) {
    __syncthreads();  // previous tile's readers done
    *(float4*)&Ks[(krow + 0 * 16) * KS_LD + kcol] = k0;
    *(float4*)&Ks[(krow + 1 * 16) * KS_LD + kcol] = k1;
    *(float4*)&Ks[(krow + 2 * 16) * KS_LD + kcol] = k2;
    *(float4*)&Ks[(krow + 3 * 16) * KS_LD + kcol] = k3;
    *(float4*)&Vts[(vrow + 0 * 32) * VS_LD + vcol] = v0;
    *(float4*)&Vts[(vrow + 1 * 32) * VS_LD + vcol] = v1;
    *(float4*)&Vts[(vrow + 2 * 32) * VS_LD + vcol] = v2;
    *(float4*)&Vts[(vrow + 3 * 32) * VS_LD + vcol] = v3;
    if (kt + 1 < nkt) {
      const unsigned short* kp = kptr + (size_t)(kt + 1) * 64 * HD_;
      k0 = *(const float4*)(kp + 0 * 16 * HD_);
      k1 = *(const float4*)(kp + 1 * 16 * HD_);
      k2 = *(const float4*)(kp + 2 * 16 * HD_);
      k3 = *(const float4*)(kp + 3 * 16 * HD_);
    }
    __syncthreads();

    f32x4 sacc[4];
    for (int n = 0; n < 4; ++n)
      for (int r = 0; r < 4; ++r) sacc[n][r] = 0.f;
    __builtin_amdgcn_s_setprio(1);
#pragma unroll
    for (int n = 0; n < 4; ++n) {
      const unsigned short* krow_p = &Ks[(n * 16 + rowq) * KS_LD + koff];
      sacc[n] = __builtin_amdgcn_mfma_f32_16x16x32_bf16(qf0, *(const bf16x8*)(krow_p + 0 * 32), sacc[n], 0, 0, 0);
      sacc[n] = __builtin_amdgcn_mfma_f32_16x16x32_bf16(qf1, *(const bf16x8*)(krow_p + 1 * 32), sacc[n], 0, 0, 0);
      sacc[n] = __builtin_amdgcn_mfma_f32_16x16x32_bf16(qf2, *(const bf16x8*)(krow_p + 2 * 32), sacc[n], 0, 0, 0);
      sacc[n] = __builtin_amdgcn_mfma_f32_16x16x32_bf16(qf3, *(const bf16x8*)(krow_p + 3 * 32), sacc[n], 0, 0, 0);
    }
    __builtin_amdgcn_s_setprio(0);

    float tmax[4] = {-3e38f, -3e38f, -3e38f, -3e38f};
    if (kt == qt) {
      for (int n = 0; n < 4; ++n) {
        int col = n * 16 + rowq;
        for (int r = 0; r < 4; ++r) {
          int row = w * 16 + lr0 + r;
          float x = (col <= row) ? sacc[n][r] : -1e30f;
          sacc[n][r] = x;
          tmax[r] = fmaxf(tmax[r], x);
        }
      }
    } else {
      for (int n = 0; n < 4; ++n)
        for (int r = 0; r < 4; ++r)
          tmax[r] = fmaxf(tmax[r], sacc[n][r]);
    }
    for (int off = 1; off < 16; off <<= 1)
      for (int r = 0; r < 4; ++r) tmax[r] = fmaxf(tmax[r], __shfl_xor(tmax[r], off));

    // T13 defer-max: rescale only if some row's max grew by >8 (exp2 units)
    float ex = -1.f;
    for (int r = 0; r < 4; ++r) ex = fmaxf(ex, tmax[r] - m_r[r]);
    if (__any(ex > 8.f)) {
      for (int r = 0; r < 4; ++r) {
        float mn = fmaxf(m_r[r], tmax[r]);
        float a = __builtin_amdgcn_exp2f(m_r[r] - mn);
        m_r[r] = mn;
        l_r[r] *= a;
        for (int nd = 0; nd < 8; ++nd) oacc[nd][r] *= a;
      }
    }
    float rs[4] = {0.f, 0.f, 0.f, 0.f};
    for (int n = 0; n < 4; ++n)
      for (int r = 0; r < 4; ++r) {
        float p = __builtin_amdgcn_exp2f(sacc[n][r] - m_r[r]);
        sacc[n][r] = p;
        rs[r] += p;
      }
    for (int off = 1; off < 16; off <<= 1)
      for (int r = 0; r < 4; ++r) rs[r] += __shfl_xor(rs[r], off);
    for (int r = 0; r < 4; ++r) l_r[r] += rs[r];

    if (kt + 1 < nkt) {
      const unsigned short* vp = vptr + (size_t)(kt + 1) * 64;
      v0 = *(const float4*)(vp + 0 * 32 * S_);
      v1 = *(const float4*)(vp + 1 * 32 * S_);
      v2 = *(const float4*)(vp + 2 * 32 * S_);
      v3 = *(const float4*)(vp + 3 * 32 * S_);
    }

    unsigned short* pw = &Ps[w * 16 * PS_LD];
    for (int n = 0; n < 4; ++n)
      for (int r = 0; r < 4; ++r)
        pw[(lr0 + r) * PS_LD + n * 16 + rowq] = f2bf(sacc[n][r]);

    __builtin_amdgcn_s_setprio(1);
#pragma unroll
    for (int t2 = 0; t2 < 2; ++t2) {
      bf16x8 pa = *(const bf16x8*)&pw[rowq * PS_LD + t2 * 32 + koff];
      for (int nd = 0; nd < 8; ++nd) {
        bf16x8 vb = *(const bf16x8*)&Vts[(nd * 16 + rowq) * VS_LD + t2 * 32 + koff];
        oacc[nd] = __builtin_amdgcn_mfma_f32_16x16x32_bf16(pa, vb, oacc[nd], 0, 0, 0);
      }
    }
    __builtin_amdgcn_s_setprio(0);
  }

  float linv[4];
  for (int r = 0; r < 4; ++r) linv[r] = __builtin_amdgcn_rcpf(l_r[r]);
  for (int nd = 0; nd < 8; ++nd) {
    int col = h * HD_ + nd * 16 + rowq;
    for (int r = 0; r < 4; ++r) {
      int row = q0 + w * 16 + lr0 + r;
      Ob[(size_t)(b * S_ + row) * HID_ + col] = f2bf(oacc[nd][r] * linv[r]);
    }
  }
}

// ---------------- launcher ----------------
extern "C" void kernel_launch(void* const* d_in, const int* in_sizes, int n_in,
                              void* d_out, int out_size, void* d_ws, size_t ws_size,
                              hipStream_t stream) {
  (void)in_sizes; (void)n_in; (void)out_size; (void)ws_size;
  const float* hidden = (const float*)d_in[0];
  // d_in[1] = attention_mask (causal; reproduced analytically)
  const int* pos = (const int*)d_in[2];
  const float* Wq = (const float*)d_in[3];
  const float* Wk = (const float*)d_in[4];
  const float* Wv = (const float*)d_in[5];
  const float* Wo = (const float*)d_in[6];
  float* out = (float*)d_out;

  char* ws = (char*)d_ws;
  unsigned short* Xb   = (unsigned short*)(ws);               // 16 MB  (B,S,HID) bf16
  unsigned short* Wqb  = (unsigned short*)(ws + 16777216);    // 8 MB  Wq -- Wqb/Wkb/Wvb contiguous:
  unsigned short* Wkb  = (unsigned short*)(ws + 25165824);    // 8 MB  Wk -- one (6144,2048) QKV weight
  unsigned short* Wvb  = (unsigned short*)(ws + 33554432);    // 8 MB  Wv
  unsigned short* Wob  = (unsigned short*)(ws + 41943040);    // 8 MB
  unsigned short* Qb   = (unsigned short*)(ws + 50331648);    // 16 MB (B,NH,S,HD)
  unsigned short* Kb   = (unsigned short*)(ws + 67108864);    // 16 MB
  unsigned short* Vtmp = (unsigned short*)(ws + 83886080);    // 16 MB (B,S,HID)
  unsigned short* Vtb  = (unsigned short*)(ws + 100663296);   // 16 MB (B,NH,HD,S)
  unsigned short* Ob   = Xb;          // Xb dead after QKV GEMM

  cast_all<<<2048, 256, 0, stream>>>(hidden, Wq, Wk, Wv, Wo, Xb, Wqb, Wkb, Wvb, Wob);

  // fused QKV: C (4096 x 6144) = X (4096x2048) * Wqkv^T, 256x192 tiles
  dim3 gq(3 * HID_ / 192, (B_ * S_) / 256);  // (32, 16) = 512 blocks = exactly 2 rounds
  gemm_qkv<<<gq, 512, 0, stream>>>(Xb, Wqb, Qb, Kb, Vtmp);

  // fused RoPE (inline trig) + V transpose: one launch, disjoint work
  rope_transpose<<<ROPE_BLOCKS_ + TRANS_BLOCKS_, 256, 0, stream>>>(Qb, Kb, pos, Vtmp, Vtb);

  dim3 ag(B_ * NH_, S_ / 64);  // bh fast, qt slow (descending inside kernel)
  attn_fused<<<ag, 256, 0, stream>>>(Qb, Kb, Vtb, Ob);

  dim3 go(HID_ / 128, (B_ * S_) / 256);  // (16, 16) = 256 blocks = exactly 1 round
  gemm_out<<<go, 512, 0, stream>>>(Ob, Wob, out);
}